// Round 14
// baseline (282.886 us; speedup 1.0000x reference)
//
#include <hip/hip_runtime.h>
#include <hip/hip_bf16.h>
#include <stdint.h>

#define DM 1024   // d_model
#define DD 512    // d (proj out / head dim)
#define BB 32     // batch
#define LL 1024   // seq len
#define SCALE 0.04419417382415922f  // 1/sqrt(512)
#define MAT ((size_t)BB * LL * DD)  // elems per q/k/v matrix

typedef float f32x4 __attribute__((ext_vector_type(4)));
typedef short bf16x8 __attribute__((ext_vector_type(8)));
typedef short bf16x4 __attribute__((ext_vector_type(4)));

__device__ inline unsigned short f2bf(float f) {
    union { float f; uint32_t u; } v; v.f = f;
    uint32_t r = v.u + 0x7fffu + ((v.u >> 16) & 1u);
    return (unsigned short)(r >> 16);
}
__device__ inline float bf2f(unsigned short u) {
    union { uint32_t u; float f; } v; v.u = ((uint32_t)u) << 16;
    return v.f;
}

__device__ inline bf16x4 cvt4(f32x4 a, float s) {
    bf16x4 r;
    r[0] = (short)f2bf(a[0] * s);
    r[1] = (short)f2bf(a[1] * s);
    r[2] = (short)f2bf(a[2] * s);
    r[3] = (short)f2bf(a[3] * s);
    return r;
}

#define GLOAD_LDS16(gsrc, ldst) \
    __builtin_amdgcn_global_load_lds((const __attribute__((address_space(1))) unsigned int*)(gsrc), \
        (__attribute__((address_space(3))) unsigned int*)(ldst), 16, 0, 0)

__device__ inline void publish_barrier() {
    asm volatile("s_waitcnt vmcnt(0)" ::: "memory");
    __builtin_amdgcn_sched_barrier(0);
    __builtin_amdgcn_s_barrier();
    __builtin_amdgcn_sched_barrier(0);
}
__device__ inline void gateB() {
    __builtin_amdgcn_sched_barrier(0);
    __builtin_amdgcn_s_barrier();
    __builtin_amdgcn_sched_barrier(0);
}
// proj7 P0 gate: all B gload_lds landed + own A ds_writes drained (visibility)
__device__ inline void gate0L() {
    asm volatile("s_waitcnt vmcnt(0) lgkmcnt(0)" ::: "memory");
    __builtin_amdgcn_sched_barrier(0);
    __builtin_amdgcn_s_barrier();
    __builtin_amdgcn_sched_barrier(0);
}
// proj7 P3: wait the 8 A f32 loads (oldest), keep B's 4 gload_lds in flight
__device__ inline void waitA() {
    asm volatile("s_waitcnt vmcnt(4)" ::: "memory");
    __builtin_amdgcn_sched_barrier(0);
}

// ---------------------------------------------------------------------------
// Kernel 0: cast W only (x-cast is fused into qkv_proj7).
// Wq pre-scaled by 1/sqrt(D). 768 blocks.
// ---------------------------------------------------------------------------
__global__ __launch_bounds__(256) void cast_w(const float* __restrict__ Wq,
                                              const float* __restrict__ Wk,
                                              const float* __restrict__ Wv,
                                              unsigned short* __restrict__ Wb)
{
    size_t idx = (size_t)blockIdx.x * 256 + threadIdx.x;   // 0..196607
    int o = (int)(idx >> 16);
    size_t rem = idx & 65535;
    const float* W = (o == 0) ? Wq : (o == 1) ? Wk : Wv;
    float s = (o == 0) ? SCALE : 1.0f;
    size_t base = rem * 8;
    f32x4 a = *(const f32x4*)(W + base);
    f32x4 b = *(const f32x4*)(W + base + 4);
    bf16x4 lo = cvt4(a, s), hi = cvt4(b, s);
    bf16x8 out = {lo[0], lo[1], lo[2], lo[3], hi[0], hi[1], hi[2], hi[3]};
    *(bf16x8*)(Wb + (size_t)o * 524288 + base) = out;
}

// ---------------------------------------------------------------------------
// Kernel 1: q/k/v projection v7 — 8-phase 256x256 structure with the x-cast
// FUSED: A-operand read as fp32 from x, converted in-register, ds_written to
// the same LDS image the gload_lds path produced (linear dest, pre-swizzled
// source). Ledger (steady state, per wave):
//  P0: gate [vmcnt(0)+lgkmcnt(0)+bar]  (B(t) landed; A-writes(t) visible)
//      issue 8x f32x4 A-loads(t+1); frags A0,B0 + B1 prefetch; MFMA Q0.
//  P1: bar; stage B0(t+1) gload_lds; MFMA Q1; backload A1 frags.
//  P2: bar; stage B1(t+1) gload_lds; MFMA Q2.
//  P3: bar; vmcnt(4) [pops exactly the 8 A-loads, B's 4 stay in flight];
//      cvt 32 floats -> 4x ds_write_b128 into buf cn; MFMA Q3.
// WAR: AL[cn][0] last read P0(t-1), AL[cn][1] last read P1(t-1); BL[cn][*]
// last read P0(t-1) — all >=2 barriers before overwrite. V output (o==2):
// LDS-transpose epilogue -> vt[b][d][l].
// ---------------------------------------------------------------------------
__global__ __launch_bounds__(512, 2) void qkv_proj7(
    const float* __restrict__ xf,         // x fp32 [32768][1024]
    const unsigned short* __restrict__ Wb,
    const float* __restrict__ bq, const float* __restrict__ bk, const float* __restrict__ bv,
    unsigned short* __restrict__ qkv,     // q at 0, k at MAT
    unsigned short* __restrict__ vt)      // [b][d][l]
{
    __shared__ __align__(16) unsigned short AL[2][2][8192];
    __shared__ __align__(16) unsigned short BL[2][2][8192];

    const int o = blockIdx.y;
    const float* bias = (o == 0) ? bq : (o == 1) ? bk : bv;
    const float wscale = (o == 0) ? SCALE : 1.0f;
    const unsigned short* W = Wb + (size_t)o * 524288;
    unsigned short* out = qkv + (size_t)o * MAT;   // used for o==0,1

    int wg = blockIdx.x;
    wg = (wg & 7) * 32 + (wg >> 3);
    const int mt = wg >> 1, nt = wg & 1;
    const int rowbase = mt * 256;
    const int colbase = nt * 256;

    const int tid  = threadIdx.x;
    const int lane = tid & 63;
    const int w    = tid >> 6;
    const int wm   = w >> 2;
    const int wn   = w & 3;
    const int l15  = lane & 15, l4 = lane >> 4;
    const int rxor = l15 & 7;

    const int r8   = lane >> 3;
    const int swch = (lane & 7) ^ r8;

    const char* xpanelf = (const char*)(xf + (size_t)rowbase * DM);  // row = 4096 B
    const char* wpanel  = (const char*)(W  + (size_t)colbase * DM);  // row = 2048 B

    // B half-tile stage via gload_lds (2 instrs/thread)
    #define STAGE_B(T, H, slot) do {                                             \
        _Pragma("unroll")                                                        \
        for (int i2 = 0; i2 < 2; ++i2) {                                         \
            int grp = i2 * 8 + w;                                                \
            GLOAD_LDS16(wpanel + ((size_t)((H) * 128 + grp * 8 + r8) * 2048)     \
                            + (size_t)(T) * 128 + swch * 16,                     \
                        (char*)(slot) + grp * 1024);                             \
        }                                                                        \
    } while (0)

    // A both halves: 8x f32x4 loads (same elements as the bf16 image)
    #define LOAD_A(T) do {                                                       \
        _Pragma("unroll")                                                        \
        for (int H = 0; H < 2; ++H)                                              \
            _Pragma("unroll")                                                    \
            for (int i2 = 0; i2 < 2; ++i2) {                                     \
                int grp = i2 * 8 + w;                                            \
                const char* src = xpanelf                                        \
                    + ((size_t)(H * 128 + grp * 8 + r8) * 4096)                  \
                    + (size_t)(T) * 256 + swch * 32;                             \
                av[H * 4 + i2 * 2]     = *(const f32x4*)(src);                   \
                av[H * 4 + i2 * 2 + 1] = *(const f32x4*)(src + 16);              \
            }                                                                    \
    } while (0)

    // cvt + ds_write into the gload_lds-identical LDS image
    #define CVT_WRITE_A(BUF) do {                                                \
        _Pragma("unroll")                                                        \
        for (int H = 0; H < 2; ++H)                                              \
            _Pragma("unroll")                                                    \
            for (int i2 = 0; i2 < 2; ++i2) {                                     \
                int grp = i2 * 8 + w;                                            \
                bf16x4 lo = cvt4(av[H * 4 + i2 * 2], 1.0f);                      \
                bf16x4 hi = cvt4(av[H * 4 + i2 * 2 + 1], 1.0f);                  \
                bf16x8 ov = {lo[0], lo[1], lo[2], lo[3],                         \
                             hi[0], hi[1], hi[2], hi[3]};                        \
                *(bf16x8*)((char*)&AL[BUF][H][0] + grp * 1024 + lane * 16) = ov; \
            }                                                                    \
    } while (0)

    #define RDA(base, mf4, ks) (*(const bf16x8*)((base) + (wm * 64 + (mf4) * 16 + l15) * 128 \
                            + ((((ks) * 4 + l4) ^ rxor) << 4)))
    #define RDB(base, nfl, ks) (*(const bf16x8*)((base) + (wn * 32 + (nfl) * 16 + l15) * 128 \
                            + ((((ks) * 4 + l4) ^ rxor) << 4)))

    f32x4 acc[8][4];
    #pragma unroll
    for (int i = 0; i < 8; ++i)
        #pragma unroll
        for (int j = 0; j < 4; ++j)
            acc[i][j] = (f32x4){0.f, 0.f, 0.f, 0.f};

    bf16x8 aF[4][2], bF[4][2];
    f32x4 av[8];

    // ---- prologue: tile 0 ----
    LOAD_A(0);                              // queue: A:8
    STAGE_B(0, 0, &BL[0][0][0]);            // +2
    STAGE_B(0, 1, &BL[0][1][0]);            // +2 -> 12
    waitA();                                // vmcnt(4): A landed (B's 4 fly)
    CVT_WRITE_A(0);
    __syncthreads();                        // drains vmcnt+lgkm: B landed, A visible

    for (int t = 0; t < 16; ++t) {
        const int c = t & 1, cn = c ^ 1;
        const char* A0b = (const char*)&AL[c][0][0];
        const char* A1b = (const char*)&AL[c][1][0];
        const char* B0b = (const char*)&BL[c][0][0];
        const char* B1b = (const char*)&BL[c][1][0];
        const bool st = (t < 15);

        // ---- phase 0: (A0,B0) ----
        gate0L();
        if (st) LOAD_A(t + 1);
        #pragma unroll
        for (int ks = 0; ks < 2; ++ks) {
            #pragma unroll
            for (int mf = 0; mf < 4; ++mf) aF[mf][ks] = RDA(A0b, mf, ks);
            bF[0][ks] = RDB(B0b, 0, ks);
            bF[1][ks] = RDB(B0b, 1, ks);
        }
        #pragma unroll
        for (int ks = 0; ks < 2; ++ks) {          // prefetch B1 frags (used in Q1)
            bF[2][ks] = RDB(B1b, 0, ks);
            bF[3][ks] = RDB(B1b, 1, ks);
        }
        #pragma unroll
        for (int ks = 0; ks < 2; ++ks)
            #pragma unroll
            for (int nf = 0; nf < 2; ++nf)
                #pragma unroll
                for (int mf = 0; mf < 4; ++mf)
                    acc[mf][nf] = __builtin_amdgcn_mfma_f32_16x16x32_bf16(aF[mf][ks], bF[nf][ks], acc[mf][nf], 0, 0, 0);

        // ---- phase 1: (A0,B1) ----
        gateB();
        if (st) STAGE_B(t + 1, 0, &BL[cn][0][0]);
        #pragma unroll
        for (int ks = 0; ks < 2; ++ks)
            #pragma unroll
            for (int nf = 0; nf < 2; ++nf)
                #pragma unroll
                for (int mf = 0; mf < 4; ++mf)
                    acc[mf][2 + nf] = __builtin_amdgcn_mfma_f32_16x16x32_bf16(aF[mf][ks], bF[2 + nf][ks], acc[mf][2 + nf], 0, 0, 0);
        #pragma unroll
        for (int ks = 0; ks < 2; ++ks)            // back-load A1 frags (Q2/Q3)
            #pragma unroll
            for (int mf = 0; mf < 4; ++mf) aF[mf][ks] = RDA(A1b, mf, ks);

        // ---- phase 2: (A1,B0) — regs only ----
        gateB();
        if (st) STAGE_B(t + 1, 1, &BL[cn][1][0]);
        #pragma unroll
        for (int ks = 0; ks < 2; ++ks)
            #pragma unroll
            for (int nf = 0; nf < 2; ++nf)
                #pragma unroll
                for (int mf = 0; mf < 4; ++mf)
                    acc[4 + mf][nf] = __builtin_amdgcn_mfma_f32_16x16x32_bf16(aF[mf][ks], bF[nf][ks], acc[4 + mf][nf], 0, 0, 0);

        // ---- phase 3: (A1,B1) — regs only; land+write A(t+1) ----
        gateB();
        if (st) { waitA(); CVT_WRITE_A(cn); }
        #pragma unroll
        for (int ks = 0; ks < 2; ++ks)
            #pragma unroll
            for (int nf = 0; nf < 2; ++nf)
                #pragma unroll
                for (int mf = 0; mf < 4; ++mf)
                    acc[4 + mf][2 + nf] = __builtin_amdgcn_mfma_f32_16x16x32_bf16(aF[mf][ks], bF[2 + nf][ks], acc[4 + mf][2 + nf], 0, 0, 0);
    }
    #undef STAGE_B
    #undef LOAD_A
    #undef CVT_WRITE_A
    #undef RDA
    #undef RDB

    if (o != 2) {
        #pragma unroll
        for (int nf = 0; nf < 4; ++nf) {
            int col = colbase + ((nf < 2) ? wn * 32 + nf * 16 : 128 + wn * 32 + (nf - 2) * 16) + l15;
            float bv_ = bias[col] * wscale;
            #pragma unroll
            for (int mf = 0; mf < 8; ++mf) {
                int row0 = rowbase + ((mf < 4) ? wm * 64 + mf * 16 : 128 + wm * 64 + (mf - 4) * 16) + l4 * 4;
                #pragma unroll
                for (int r = 0; r < 4; ++r)
                    out[(size_t)(row0 + r) * DD + col] = f2bf(acc[mf][nf][r] + bv_);
            }
        }
    } else {
        // ---- V epilogue: transpose 256x256 tile via LDS -> vt[b][d][l] ----
        unsigned short* ldsT = (unsigned short*)&AL[0][0][0];
        const int bidx  = rowbase >> 10;
        const int lbase = rowbase & 1023;
        #pragma unroll
        for (int p = 0; p < 4; ++p) {
            __syncthreads();
            #pragma unroll
            for (int nf = 0; nf < 4; ++nf) {
                int base16 = (nf < 2) ? wn * 32 + nf * 16 : 128 + wn * 32 + (nf - 2) * 16;
                if (base16 >= p * 64 && base16 < p * 64 + 64) {
                    int cc = base16 - p * 64 + l15;
                    float bv_ = bias[colbase + base16 + l15];
                    #pragma unroll
                    for (int mf = 0; mf < 8; ++mf) {
                        int rowl = ((mf < 4) ? wm * 64 + mf * 16 : 128 + wm * 64 + (mf - 4) * 16) + l4 * 4;
                        bf16x4 v4;
                        #pragma unroll
                        for (int r = 0; r < 4; ++r)
                            v4[r] = (short)f2bf(acc[mf][nf][r] + bv_);
                        *(bf16x4*)&ldsT[cc * 264 + rowl] = v4;
                    }
                }
            }
            __syncthreads();
            #pragma unroll
            for (int it = 0; it < 4; ++it) {
                int uu = tid + it * 512;
                int cc = uu >> 5;
                int r0 = (uu & 31) * 8;
                bf16x8 val = *(const bf16x8*)&ldsT[cc * 264 + r0];
                int dg = colbase + p * 64 + cc;
                *(bf16x8*)(vt + ((size_t)(bidx * DD + dg)) * LL + lbase + r0) = val;
            }
        }
    }
}

// ---------------------------------------------------------------------------
// Kernel 3: S = q . k^T, lower-triangle 128x128 tiles (unchanged).
// ---------------------------------------------------------------------------
__global__ __launch_bounds__(256, 2) void sgemm_qk(
    const unsigned short* __restrict__ qkv,
    unsigned short* __restrict__ S)
{
    __shared__ __align__(16) unsigned short At[2][8192];
    __shared__ __align__(16) unsigned short Bt[2][8192];

    int wg = blockIdx.x;
    wg = (wg & 7) * 144 + (wg >> 3);
    const int b = wg / 36;
    const int t36 = wg % 36;
    int mt = 0, accq = 0;
    while (accq + mt + 1 <= t36) { ++mt; accq += mt; }
    const int nt = t36 - accq;

    const int tid  = threadIdx.x;
    const int lane = tid & 63;
    const int w    = tid >> 6;
    const int wr   = (w >> 1) * 64;
    const int wc   = (w & 1) * 64;
    const int l15  = lane & 15, l4 = lane >> 4;

    const int r8   = lane >> 3;
    const int swch = (lane & 7) ^ r8;

    const unsigned short* q = qkv;
    const unsigned short* k = qkv + MAT;
    const char* apanel = (const char*)(q + ((size_t)(b * LL) + mt * 128) * DD);
    const char* bpanel = (const char*)(k + ((size_t)(b * LL) + nt * 128) * DD);

    f32x4 acc[4][4];
    #pragma unroll
    for (int i = 0; i < 4; ++i)
        #pragma unroll
        for (int j = 0; j < 4; ++j)
            acc[i][j] = (f32x4){0.f, 0.f, 0.f, 0.f};

    #define STAGE_QK(KK, BUF) do {                                               \
        _Pragma("unroll")                                                        \
        for (int i2 = 0; i2 < 4; ++i2) {                                         \
            int grp = i2 * 4 + w;                                                \
            size_t rowoff = (size_t)(grp * 8 + r8) * 1024 + (KK) * 2 + swch * 16;\
            GLOAD_LDS16(apanel + rowoff, (char*)&At[BUF][0] + grp * 1024);       \
            GLOAD_LDS16(bpanel + rowoff, (char*)&Bt[BUF][0] + grp * 1024);       \
        }                                                                        \
    } while (0)

    STAGE_QK(0, 0);
    __syncthreads();

    for (int t = 0; t < 8; ++t) {
        const int cur = t & 1;
        if (t < 7) STAGE_QK((t + 1) * 64, cur ^ 1);

        const char* Ab = (const char*)&At[cur][0];
        const char* Bb = (const char*)&Bt[cur][0];
        #pragma unroll
        for (int ks = 0; ks < 2; ++ks) {
            bf16x8 af[4], bf_[4];
            const int ch = (ks * 4 + l4) ^ (l15 & 7);
            #pragma unroll
            for (int m = 0; m < 4; ++m)
                af[m] = *(const bf16x8*)(Ab + (wr + m * 16 + l15) * 128 + (ch << 4));
            #pragma unroll
            for (int n = 0; n < 4; ++n)
                bf_[n] = *(const bf16x8*)(Bb + (wc + n * 16 + l15) * 128 + (ch << 4));
            #pragma unroll
            for (int n = 0; n < 4; ++n)
                #pragma unroll
                for (int m = 0; m < 4; ++m)
                    acc[m][n] = __builtin_amdgcn_mfma_f32_16x16x32_bf16(af[m], bf_[n], acc[m][n], 0, 0, 0);
        }

        if (t < 7) publish_barrier();
    }
    #undef STAGE_QK

    unsigned short* sp = S + ((size_t)(b * LL) + mt * 128) * LL + nt * 128;
    #pragma unroll
    for (int n = 0; n < 4; ++n) {
        int col = wc + n * 16 + l15;
        #pragma unroll
        for (int m = 0; m < 4; ++m) {
            int row0 = wr + m * 16 + l4 * 4;
            #pragma unroll
            for (int r = 0; r < 4; ++r)
                sp[(size_t)(row0 + r) * LL + col] = f2bf(acc[m][n][r]);
        }
    }
}

// ---------------------------------------------------------------------------
// Kernel 4: row softmax v2 (unchanged from round 13).
// ---------------------------------------------------------------------------
__global__ __launch_bounds__(256) void softmax_rows(
    const unsigned short* __restrict__ S,
    const int* __restrict__ mask,
    unsigned short* __restrict__ P)
{
    __shared__ float mbias[1024];
    const int rc = blockIdx.x, b = blockIdx.y;
    const int tid = threadIdx.x, lane = tid & 63, w = tid >> 6;

    {
        const int* mp = mask + b * LL;
        #pragma unroll
        for (int j = 0; j < 4; ++j)
            mbias[tid * 4 + j] = mp[tid * 4 + j] ? 0.0f : -1e30f;
    }
    __syncthreads();

    const int j0 = lane * 16;
    const int limit = ((rc >> 2) + 1) << 7;
    for (int i = 0; i < 8; ++i) {
        const int r = rc * 32 + i * 4 + w;
        const unsigned short* srow = S + ((size_t)(b * LL) + r) * LL;

        bf16x8 v0 = {0,0,0,0,0,0,0,0}, v1 = {0,0,0,0,0,0,0,0};
        if (j0 <= r)     v0 = *(const bf16x8*)(srow + j0);
        if (j0 + 8 <= r) v1 = *(const bf16x8*)(srow + j0 + 8);

        float s[16];
        #pragma unroll
        for (int e = 0; e < 8; ++e) {
            int j = j0 + e;
            s[e]     = (j <= r)     ? bf2f((unsigned short)v0[e]) + mbias[j]     : -3e38f;
            s[8 + e] = (j + 8 <= r) ? bf2f((unsigned short)v1[e]) + mbias[j + 8] : -3e38f;
        }
        float mx = s[0];
        #pragma unroll
        for (int e = 1; e < 16; ++e) mx = fmaxf(mx, s[e]);
        mx = fmaxf(mx, __shfl_xor(mx, 1));
        mx = fmaxf(mx, __shfl_xor(mx, 2));
        mx = fmaxf(mx, __shfl_xor(mx, 4));
        mx = fmaxf(mx, __shfl_xor(mx, 8));
        mx = fmaxf(mx, __shfl_xor(mx, 16));
        mx = fmaxf(mx, __shfl_xor(mx, 32));

        float p[16], ls = 0.f;
        #pragma unroll
        for (int e = 0; e < 16; ++e) { p[e] = __expf(s[e] - mx); ls += p[e]; }
        ls += __shfl_xor(ls, 1);
        ls += __shfl_xor(ls, 2);
        ls += __shfl_xor(ls, 4);
        ls += __shfl_xor(ls, 8);
        ls += __shfl_xor(ls, 16);
        ls += __shfl_xor(ls, 32);
        const float inv = 1.0f / ls;

        if (j0 < limit) {
            bf16x8 o0, o1;
            #pragma unroll
            for (int e = 0; e < 8; ++e) {
                o0[e] = (short)f2bf(p[e] * inv);
                o1[e] = (short)f2bf(p[8 + e] * inv);
            }
            unsigned short* prow = P + ((size_t)(b * LL) + r) * LL;
            *(bf16x8*)(prow + j0)     = o0;
            *(bf16x8*)(prow + j0 + 8) = o1;
        }
    }
}

// ---------------------------------------------------------------------------
// Kernel 5: O = relu(P . V) via vt (unchanged).
// ---------------------------------------------------------------------------
__global__ __launch_bounds__(256, 2) void pv_gemm(
    const unsigned short* __restrict__ P,
    const unsigned short* __restrict__ vt,
    float* __restrict__ outp)
{
    __shared__ __align__(16) unsigned short At[2][8192];
    __shared__ __align__(16) unsigned short Bt[2][8192];

    int wg = blockIdx.x;
    wg = (wg & 7) * 128 + (wg >> 3);
    const int b  = wg >> 5;
    const int rr = wg & 31;
    const int rt = 7 - (rr >> 2);
    const int ct = rr & 3;

    const int tid  = threadIdx.x;
    const int lane = tid & 63;
    const int w    = tid >> 6;
    const int wr   = (w >> 1) * 64;
    const int wc   = (w & 1) * 64;
    const int l15  = lane & 15, l4 = lane >> 4;

    const int r8   = lane >> 3;
    const int swch = (lane & 7) ^ r8;

    const char* apanel = (const char*)(P  + ((size_t)(b * LL) + rt * 128) * LL);
    const char* bpanel = (const char*)(vt + ((size_t)(b * DD) + ct * 128) * LL);

    const int NT = (rt + 1) * 2;

    f32x4 acc[4][4];
    #pragma unroll
    for (int i = 0; i < 4; ++i)
        #pragma unroll
        for (int j = 0; j < 4; ++j)
            acc[i][j] = (f32x4){0.f, 0.f, 0.f, 0.f};

    #define STAGE_PV(KK, BUF) do {                                               \
        _Pragma("unroll")                                                        \
        for (int i2 = 0; i2 < 4; ++i2) {                                         \
            int grp = i2 * 4 + w;                                                \
            size_t rowoff = (size_t)(grp * 8 + r8) * 2048 + (KK) * 2 + swch * 16;\
            GLOAD_LDS16(apanel + rowoff, (char*)&At[BUF][0] + grp * 1024);       \
            GLOAD_LDS16(bpanel + rowoff, (char*)&Bt[BUF][0] + grp * 1024);       \
        }                                                                        \
    } while (0)

    STAGE_PV(0, 0);
    __syncthreads();

    for (int t = 0; t < NT; ++t) {
        const int cur = t & 1;
        if (t < NT - 1) STAGE_PV((t + 1) * 64, cur ^ 1);

        const char* Ab = (const char*)&At[cur][0];
        const char* Bb = (const char*)&Bt[cur][0];
        #pragma unroll
        for (int ks = 0; ks < 2; ++ks) {
            bf16x8 af[4], bf_[4];
            const int ch = (ks * 4 + l4) ^ (l15 & 7);
            #pragma unroll
            for (int m = 0; m < 4; ++m)
                af[m] = *(const bf16x8*)(Ab + (wr + m * 16 + l15) * 128 + (ch << 4));
            #pragma unroll
            for (int n = 0; n < 4; ++n)
                bf_[n] = *(const bf16x8*)(Bb + (wc + n * 16 + l15) * 128 + (ch << 4));
            #pragma unroll
            for (int n = 0; n < 4; ++n)
                #pragma unroll
                for (int m = 0; m < 4; ++m)
                    acc[m][n] = __builtin_amdgcn_mfma_f32_16x16x32_bf16(af[m], bf_[n], acc[m][n], 0, 0, 0);
        }

        if (t < NT - 1) publish_barrier();
    }
    #undef STAGE_PV

    float* op = outp + ((size_t)(b * LL) + rt * 128) * DD + ct * 128;
    #pragma unroll
    for (int n = 0; n < 4; ++n) {
        int col = wc + n * 16 + l15;
        #pragma unroll
        for (int m = 0; m < 4; ++m) {
            int row0 = wr + m * 16 + l4 * 4;
            #pragma unroll
            for (int r = 0; r < 4; ++r)
                op[(size_t)(row0 + r) * DD + col] = fmaxf(acc[m][n][r], 0.f);
        }
    }
}

extern "C" void kernel_launch(void* const* d_in, const int* in_sizes, int n_in,
                              void* d_out, int out_size, void* d_ws, size_t ws_size,
                              hipStream_t stream) {
    const float* x  = (const float*)d_in[0];
    const float* Wq = (const float*)d_in[1];
    const float* bq = (const float*)d_in[2];
    const float* Wk = (const float*)d_in[3];
    const float* bk = (const float*)d_in[4];
    const float* Wv = (const float*)d_in[5];
    const float* bv = (const float*)d_in[6];
    const int* mask = (const int*)d_in[7];

    unsigned short* qkv = (unsigned short*)d_ws;          // q | k (2 x 32MB)
    unsigned short* vtp = qkv + 2 * MAT;                  // vt [b][d][l] (32MB)
    unsigned short* Wb  = qkv + 3 * MAT;                  // W bf16 (3MB)
    unsigned short* S   = (unsigned short*)d_out;         // S bf16 (64MB)
    unsigned short* Pp  = qkv;                            // P bf16 over q+k (dead)
    float* out = (float*)d_out;                           // final O overwrites S

    cast_w<<<768, 256, 0, stream>>>(Wq, Wk, Wv, Wb);
    qkv_proj7<<<dim3(256, 3), 512, 0, stream>>>(x, Wb, bq, bk, bv, qkv, vtp);
    sgemm_qk<<<dim3(1152), 256, 0, stream>>>(qkv, S);
    softmax_rows<<<dim3(32, 32), 256, 0, stream>>>(S, mask, Pp);
    pv_gemm<<<dim3(1024), 256, 0, stream>>>(Pp, vtp, out);
}

// Round 15
// 248.778 us; speedup vs baseline: 1.1371x; 1.1371x over previous
//
#include <hip/hip_runtime.h>
#include <hip/hip_bf16.h>
#include <stdint.h>

#define DM 1024   // d_model
#define DD 512    // d (proj out / head dim)
#define BB 32     // batch
#define LL 1024   // seq len
#define SCALE 0.04419417382415922f  // 1/sqrt(512)
#define MAT ((size_t)BB * LL * DD)  // elems per q/k/v matrix

typedef float f32x4 __attribute__((ext_vector_type(4)));
typedef short bf16x8 __attribute__((ext_vector_type(8)));
typedef short bf16x4 __attribute__((ext_vector_type(4)));

__device__ inline unsigned short f2bf(float f) {
    union { float f; uint32_t u; } v; v.f = f;
    uint32_t r = v.u + 0x7fffu + ((v.u >> 16) & 1u);
    return (unsigned short)(r >> 16);
}
__device__ inline float bf2f(unsigned short u) {
    union { uint32_t u; float f; } v; v.u = ((uint32_t)u) << 16;
    return v.f;
}

__device__ inline bf16x4 cvt4(f32x4 a, float s) {
    bf16x4 r;
    r[0] = (short)f2bf(a[0] * s);
    r[1] = (short)f2bf(a[1] * s);
    r[2] = (short)f2bf(a[2] * s);
    r[3] = (short)f2bf(a[3] * s);
    return r;
}

#define GLOAD_LDS16(gsrc, ldst) \
    __builtin_amdgcn_global_load_lds((const __attribute__((address_space(1))) unsigned int*)(gsrc), \
        (__attribute__((address_space(3))) unsigned int*)(ldst), 16, 0, 0)

__device__ inline void publish_barrier() {
    asm volatile("s_waitcnt vmcnt(0)" ::: "memory");
    __builtin_amdgcn_sched_barrier(0);
    __builtin_amdgcn_s_barrier();
    __builtin_amdgcn_sched_barrier(0);
}
__device__ inline void gate4() {
    asm volatile("s_waitcnt vmcnt(4)" ::: "memory");
    __builtin_amdgcn_sched_barrier(0);
    __builtin_amdgcn_s_barrier();
    __builtin_amdgcn_sched_barrier(0);
}
__device__ inline void gate2() {
    asm volatile("s_waitcnt vmcnt(2)" ::: "memory");
    __builtin_amdgcn_sched_barrier(0);
    __builtin_amdgcn_s_barrier();
    __builtin_amdgcn_sched_barrier(0);
}
__device__ inline void gate0() {
    asm volatile("s_waitcnt vmcnt(0)" ::: "memory");
    __builtin_amdgcn_sched_barrier(0);
    __builtin_amdgcn_s_barrier();
    __builtin_amdgcn_sched_barrier(0);
}
__device__ inline void gateB() {
    __builtin_amdgcn_sched_barrier(0);
    __builtin_amdgcn_s_barrier();
    __builtin_amdgcn_sched_barrier(0);
}
// full LDS-read drain before an MFMA burst (m201 template element; rule #18)
__device__ inline void lgkm0() {
    asm volatile("s_waitcnt lgkmcnt(0)" ::: "memory");
    __builtin_amdgcn_sched_barrier(0);
}

// ---------------------------------------------------------------------------
// Kernel 0: fused casts. Blocks [0,16384): x fp32->bf16 into xb.
// Blocks [16384,17152): Wq/Wk/Wv fp32->bf16 (Wq pre-scaled) into Wb.
// ---------------------------------------------------------------------------
__global__ __launch_bounds__(256) void cast_all(const float* __restrict__ x,
                                                const float* __restrict__ Wq,
                                                const float* __restrict__ Wk,
                                                const float* __restrict__ Wv,
                                                unsigned short* __restrict__ xb,
                                                unsigned short* __restrict__ Wb)
{
    int bx = blockIdx.x;
    if (bx < 16384) {
        size_t idx = (size_t)bx * 256 + threadIdx.x;
        size_t base = idx * 8;
        f32x4 a = *(const f32x4*)(x + base);
        f32x4 b = *(const f32x4*)(x + base + 4);
        bf16x4 lo = cvt4(a, 1.0f), hi = cvt4(b, 1.0f);
        bf16x8 o = {lo[0], lo[1], lo[2], lo[3], hi[0], hi[1], hi[2], hi[3]};
        *(bf16x8*)(xb + base) = o;
    } else {
        size_t idx = (size_t)(bx - 16384) * 256 + threadIdx.x;  // 0..196607
        int o = (int)(idx >> 16);
        size_t rem = idx & 65535;
        const float* W = (o == 0) ? Wq : (o == 1) ? Wk : Wv;
        float s = (o == 0) ? SCALE : 1.0f;
        size_t base = rem * 8;
        f32x4 a = *(const f32x4*)(W + base);
        f32x4 b = *(const f32x4*)(W + base + 4);
        bf16x4 lo = cvt4(a, s), hi = cvt4(b, s);
        bf16x8 out = {lo[0], lo[1], lo[2], lo[3], hi[0], hi[1], hi[2], hi[3]};
        *(bf16x8*)(Wb + (size_t)o * 524288 + base) = out;
    }
}

// ---------------------------------------------------------------------------
// Kernel 1: q/k/v projection v8 — r13's proj6 stage-order/vmcnt ledger
// (validated) restructured to the m201 phase template: per phase
//   {stage issue ∥ (reads flown from prior phase)} -> gate-barrier ->
//   lgkmcnt(0) -> setprio(1) -> MFMA burst -> setprio(0) -> trailing barrier.
// The trailing barrier phase-locks waves so stage/ds_reads of one phase
// overlap MFMA bursts of others (the role-split that makes setprio pay,
// m218b). A1 frag reads issue AFTER Q1's burst so they fly across the
// trailing barrier (reads-before-barrier). fp32-x fusion REVERTED (r14:
// FETCH 110->209MB, MfmaUtil 23). V output (o==2): LDS-transpose epilogue.
// ---------------------------------------------------------------------------
__global__ __launch_bounds__(512, 2) void qkv_proj8(
    const unsigned short* __restrict__ xb,
    const unsigned short* __restrict__ Wb,
    const float* __restrict__ bq, const float* __restrict__ bk, const float* __restrict__ bv,
    unsigned short* __restrict__ qkv,     // q at 0, k at MAT
    unsigned short* __restrict__ vt)      // [b][d][l]
{
    __shared__ __align__(16) unsigned short AL[2][2][8192];
    __shared__ __align__(16) unsigned short BL[2][2][8192];

    const int o = blockIdx.y;
    const float* bias = (o == 0) ? bq : (o == 1) ? bk : bv;
    const float wscale = (o == 0) ? SCALE : 1.0f;
    const unsigned short* W = Wb + (size_t)o * 524288;
    unsigned short* out = qkv + (size_t)o * MAT;   // used for o==0,1

    int wg = blockIdx.x;
    wg = (wg & 7) * 32 + (wg >> 3);
    const int mt = wg >> 1, nt = wg & 1;
    const int rowbase = mt * 256;
    const int colbase = nt * 256;

    const int tid  = threadIdx.x;
    const int lane = tid & 63;
    const int w    = tid >> 6;
    const int wm   = w >> 2;
    const int wn   = w & 3;
    const int l15  = lane & 15, l4 = lane >> 4;
    const int rxor = l15 & 7;

    const int r8   = lane >> 3;
    const int swch = (lane & 7) ^ r8;

    const char* xpanel = (const char*)(xb + (size_t)rowbase * DM);
    const char* wpanel = (const char*)(W  + (size_t)colbase * DM);

    #define STAGE_HALF(panel, T, H, slot) do {                                   \
        _Pragma("unroll")                                                        \
        for (int i2 = 0; i2 < 2; ++i2) {                                         \
            int grp = i2 * 8 + w;                                                \
            GLOAD_LDS16((panel) + ((size_t)((H) * 128 + grp * 8 + r8) * 2048)    \
                            + (size_t)(T) * 128 + swch * 16,                     \
                        (char*)(slot) + grp * 1024);                             \
        }                                                                        \
    } while (0)

    #define RDA(base, mf4, ks) (*(const bf16x8*)((base) + (wm * 64 + (mf4) * 16 + l15) * 128 \
                            + ((((ks) * 4 + l4) ^ rxor) << 4)))
    #define RDB(base, nfl, ks) (*(const bf16x8*)((base) + (wn * 32 + (nfl) * 16 + l15) * 128 \
                            + ((((ks) * 4 + l4) ^ rxor) << 4)))

    f32x4 acc[8][4];
    #pragma unroll
    for (int i = 0; i < 8; ++i)
        #pragma unroll
        for (int j = 0; j < 4; ++j)
            acc[i][j] = (f32x4){0.f, 0.f, 0.f, 0.f};

    bf16x8 aF[4][2], bF[4][2];

    STAGE_HALF(xpanel, 0, 0, &AL[0][0][0]);   // A0
    STAGE_HALF(wpanel, 0, 0, &BL[0][0][0]);   // B0
    STAGE_HALF(wpanel, 0, 1, &BL[0][1][0]);   // B1
    STAGE_HALF(xpanel, 0, 1, &AL[0][1][0]);   // A1

    for (int t = 0; t < 16; ++t) {
        const int c = t & 1, cn = c ^ 1;
        const char* A0b = (const char*)&AL[c][0][0];
        const char* A1b = (const char*)&AL[c][1][0];
        const char* B0b = (const char*)&BL[c][0][0];
        const char* B1b = (const char*)&BL[c][1][0];
        const bool st = (t < 15);

        // ---- phase 0: (A0,B0) ----
        if (st) { STAGE_HALF(xpanel, t + 1, 0, &AL[cn][0][0]); gate4(); } else gate2();
        #pragma unroll
        for (int ks = 0; ks < 2; ++ks) {
            #pragma unroll
            for (int mf = 0; mf < 4; ++mf) aF[mf][ks] = RDA(A0b, mf, ks);
            bF[0][ks] = RDB(B0b, 0, ks);
            bF[1][ks] = RDB(B0b, 1, ks);
        }
        #pragma unroll
        for (int ks = 0; ks < 2; ++ks) {          // B1 frags (used in Q1/Q3)
            bF[2][ks] = RDB(B1b, 0, ks);
            bF[3][ks] = RDB(B1b, 1, ks);
        }
        lgkm0();
        __builtin_amdgcn_s_setprio(1);
        #pragma unroll
        for (int ks = 0; ks < 2; ++ks)
            #pragma unroll
            for (int nf = 0; nf < 2; ++nf)
                #pragma unroll
                for (int mf = 0; mf < 4; ++mf)
                    acc[mf][nf] = __builtin_amdgcn_mfma_f32_16x16x32_bf16(aF[mf][ks], bF[nf][ks], acc[mf][nf], 0, 0, 0);
        __builtin_amdgcn_s_setprio(0);
        gateB();   // trailing barrier: phase-lock (stage/reads of others overlap this burst)

        // ---- phase 1: (A0,B1) — operands already in regs ----
        if (st) { STAGE_HALF(wpanel, t + 1, 0, &BL[cn][0][0]); gate4(); } else gate0();
        __builtin_amdgcn_s_setprio(1);
        #pragma unroll
        for (int ks = 0; ks < 2; ++ks)
            #pragma unroll
            for (int nf = 0; nf < 2; ++nf)
                #pragma unroll
                for (int mf = 0; mf < 4; ++mf)
                    acc[mf][2 + nf] = __builtin_amdgcn_mfma_f32_16x16x32_bf16(aF[mf][ks], bF[2 + nf][ks], acc[mf][2 + nf], 0, 0, 0);
        __builtin_amdgcn_s_setprio(0);
        #pragma unroll
        for (int ks = 0; ks < 2; ++ks)            // A1 frag reads fly across the barrier
            #pragma unroll
            for (int mf = 0; mf < 4; ++mf) aF[mf][ks] = RDA(A1b, mf, ks);
        gateB();   // trailing barrier (A1 reads in flight)

        // ---- phase 2: (A1,B0) ----
        if (st) STAGE_HALF(wpanel, t + 1, 1, &BL[cn][1][0]);
        gateB();
        lgkm0();   // land the A1 reads issued in P1
        __builtin_amdgcn_s_setprio(1);
        #pragma unroll
        for (int ks = 0; ks < 2; ++ks)
            #pragma unroll
            for (int nf = 0; nf < 2; ++nf)
                #pragma unroll
                for (int mf = 0; mf < 4; ++mf)
                    acc[4 + mf][nf] = __builtin_amdgcn_mfma_f32_16x16x32_bf16(aF[mf][ks], bF[nf][ks], acc[4 + mf][nf], 0, 0, 0);
        __builtin_amdgcn_s_setprio(0);
        gateB();   // trailing barrier

        // ---- phase 3: (A1,B1) — regs only ----
        if (st) STAGE_HALF(xpanel, t + 1, 1, &AL[cn][1][0]);
        gateB();
        __builtin_amdgcn_s_setprio(1);
        #pragma unroll
        for (int ks = 0; ks < 2; ++ks)
            #pragma unroll
            for (int nf = 0; nf < 2; ++nf)
                #pragma unroll
                for (int mf = 0; mf < 4; ++mf)
                    acc[4 + mf][2 + nf] = __builtin_amdgcn_mfma_f32_16x16x32_bf16(aF[mf][ks], bF[2 + nf][ks], acc[4 + mf][2 + nf], 0, 0, 0);
        __builtin_amdgcn_s_setprio(0);
        // next phase-0 gate closes the tile
    }
    #undef STAGE_HALF
    #undef RDA
    #undef RDB

    if (o != 2) {
        #pragma unroll
        for (int nf = 0; nf < 4; ++nf) {
            int col = colbase + ((nf < 2) ? wn * 32 + nf * 16 : 128 + wn * 32 + (nf - 2) * 16) + l15;
            float bv_ = bias[col] * wscale;
            #pragma unroll
            for (int mf = 0; mf < 8; ++mf) {
                int row0 = rowbase + ((mf < 4) ? wm * 64 + mf * 16 : 128 + wm * 64 + (mf - 4) * 16) + l4 * 4;
                #pragma unroll
                for (int r = 0; r < 4; ++r)
                    out[(size_t)(row0 + r) * DD + col] = f2bf(acc[mf][nf][r] + bv_);
            }
        }
    } else {
        // ---- V epilogue: transpose 256x256 tile via LDS -> vt[b][d][l] ----
        unsigned short* ldsT = (unsigned short*)&AL[0][0][0];
        const int bidx  = rowbase >> 10;
        const int lbase = rowbase & 1023;
        #pragma unroll
        for (int p = 0; p < 4; ++p) {
            __syncthreads();
            #pragma unroll
            for (int nf = 0; nf < 4; ++nf) {
                int base16 = (nf < 2) ? wn * 32 + nf * 16 : 128 + wn * 32 + (nf - 2) * 16;
                if (base16 >= p * 64 && base16 < p * 64 + 64) {
                    int cc = base16 - p * 64 + l15;
                    float bv_ = bias[colbase + base16 + l15];
                    #pragma unroll
                    for (int mf = 0; mf < 8; ++mf) {
                        int rowl = ((mf < 4) ? wm * 64 + mf * 16 : 128 + wm * 64 + (mf - 4) * 16) + l4 * 4;
                        bf16x4 v4;
                        #pragma unroll
                        for (int r = 0; r < 4; ++r)
                            v4[r] = (short)f2bf(acc[mf][nf][r] + bv_);
                        *(bf16x4*)&ldsT[cc * 264 + rowl] = v4;
                    }
                }
            }
            __syncthreads();
            #pragma unroll
            for (int it = 0; it < 4; ++it) {
                int uu = tid + it * 512;
                int cc = uu >> 5;
                int r0 = (uu & 31) * 8;
                bf16x8 val = *(const bf16x8*)&ldsT[cc * 264 + r0];
                int dg = colbase + p * 64 + cc;
                *(bf16x8*)(vt + ((size_t)(bidx * DD + dg)) * LL + lbase + r0) = val;
            }
        }
    }
}

// ---------------------------------------------------------------------------
// Kernel 3: S = q . k^T, lower-triangle 128x128 tiles (unchanged).
// ---------------------------------------------------------------------------
__global__ __launch_bounds__(256, 2) void sgemm_qk(
    const unsigned short* __restrict__ qkv,
    unsigned short* __restrict__ S)
{
    __shared__ __align__(16) unsigned short At[2][8192];
    __shared__ __align__(16) unsigned short Bt[2][8192];

    int wg = blockIdx.x;
    wg = (wg & 7) * 144 + (wg >> 3);
    const int b = wg / 36;
    const int t36 = wg % 36;
    int mt = 0, accq = 0;
    while (accq + mt + 1 <= t36) { ++mt; accq += mt; }
    const int nt = t36 - accq;

    const int tid  = threadIdx.x;
    const int lane = tid & 63;
    const int w    = tid >> 6;
    const int wr   = (w >> 1) * 64;
    const int wc   = (w & 1) * 64;
    const int l15  = lane & 15, l4 = lane >> 4;

    const int r8   = lane >> 3;
    const int swch = (lane & 7) ^ r8;

    const unsigned short* q = qkv;
    const unsigned short* k = qkv + MAT;
    const char* apanel = (const char*)(q + ((size_t)(b * LL) + mt * 128) * DD);
    const char* bpanel = (const char*)(k + ((size_t)(b * LL) + nt * 128) * DD);

    f32x4 acc[4][4];
    #pragma unroll
    for (int i = 0; i < 4; ++i)
        #pragma unroll
        for (int j = 0; j < 4; ++j)
            acc[i][j] = (f32x4){0.f, 0.f, 0.f, 0.f};

    #define STAGE_QK(KK, BUF) do {                                               \
        _Pragma("unroll")                                                        \
        for (int i2 = 0; i2 < 4; ++i2) {                                         \
            int grp = i2 * 4 + w;                                                \
            size_t rowoff = (size_t)(grp * 8 + r8) * 1024 + (KK) * 2 + swch * 16;\
            GLOAD_LDS16(apanel + rowoff, (char*)&At[BUF][0] + grp * 1024);       \
            GLOAD_LDS16(bpanel + rowoff, (char*)&Bt[BUF][0] + grp * 1024);       \
        }                                                                        \
    } while (0)

    STAGE_QK(0, 0);
    __syncthreads();

    for (int t = 0; t < 8; ++t) {
        const int cur = t & 1;
        if (t < 7) STAGE_QK((t + 1) * 64, cur ^ 1);

        const char* Ab = (const char*)&At[cur][0];
        const char* Bb = (const char*)&Bt[cur][0];
        #pragma unroll
        for (int ks = 0; ks < 2; ++ks) {
            bf16x8 af[4], bf_[4];
            const int ch = (ks * 4 + l4) ^ (l15 & 7);
            #pragma unroll
            for (int m = 0; m < 4; ++m)
                af[m] = *(const bf16x8*)(Ab + (wr + m * 16 + l15) * 128 + (ch << 4));
            #pragma unroll
            for (int n = 0; n < 4; ++n)
                bf_[n] = *(const bf16x8*)(Bb + (wc + n * 16 + l15) * 128 + (ch << 4));
            #pragma unroll
            for (int n = 0; n < 4; ++n)
                #pragma unroll
                for (int m = 0; m < 4; ++m)
                    acc[m][n] = __builtin_amdgcn_mfma_f32_16x16x32_bf16(af[m], bf_[n], acc[m][n], 0, 0, 0);
        }

        if (t < 7) publish_barrier();
    }
    #undef STAGE_QK

    unsigned short* sp = S + ((size_t)(b * LL) + mt * 128) * LL + nt * 128;
    #pragma unroll
    for (int n = 0; n < 4; ++n) {
        int col = wc + n * 16 + l15;
        #pragma unroll
        for (int m = 0; m < 4; ++m) {
            int row0 = wr + m * 16 + l4 * 4;
            #pragma unroll
            for (int r = 0; r < 4; ++r)
                sp[(size_t)(row0 + r) * LL + col] = f2bf(acc[m][n][r]);
        }
    }
}

// ---------------------------------------------------------------------------
// Kernel 4: row softmax v2 (unchanged from round 13).
// ---------------------------------------------------------------------------
__global__ __launch_bounds__(256) void softmax_rows(
    const unsigned short* __restrict__ S,
    const int* __restrict__ mask,
    unsigned short* __restrict__ P)
{
    __shared__ float mbias[1024];
    const int rc = blockIdx.x, b = blockIdx.y;
    const int tid = threadIdx.x, lane = tid & 63, w = tid >> 6;

    {
        const int* mp = mask + b * LL;
        #pragma unroll
        for (int j = 0; j < 4; ++j)
            mbias[tid * 4 + j] = mp[tid * 4 + j] ? 0.0f : -1e30f;
    }
    __syncthreads();

    const int j0 = lane * 16;
    const int limit = ((rc >> 2) + 1) << 7;
    for (int i = 0; i < 8; ++i) {
        const int r = rc * 32 + i * 4 + w;
        const unsigned short* srow = S + ((size_t)(b * LL) + r) * LL;

        bf16x8 v0 = {0,0,0,0,0,0,0,0}, v1 = {0,0,0,0,0,0,0,0};
        if (j0 <= r)     v0 = *(const bf16x8*)(srow + j0);
        if (j0 + 8 <= r) v1 = *(const bf16x8*)(srow + j0 + 8);

        float s[16];
        #pragma unroll
        for (int e = 0; e < 8; ++e) {
            int j = j0 + e;
            s[e]     = (j <= r)     ? bf2f((unsigned short)v0[e]) + mbias[j]     : -3e38f;
            s[8 + e] = (j + 8 <= r) ? bf2f((unsigned short)v1[e]) + mbias[j + 8] : -3e38f;
        }
        float mx = s[0];
        #pragma unroll
        for (int e = 1; e < 16; ++e) mx = fmaxf(mx, s[e]);
        mx = fmaxf(mx, __shfl_xor(mx, 1));
        mx = fmaxf(mx, __shfl_xor(mx, 2));
        mx = fmaxf(mx, __shfl_xor(mx, 4));
        mx = fmaxf(mx, __shfl_xor(mx, 8));
        mx = fmaxf(mx, __shfl_xor(mx, 16));
        mx = fmaxf(mx, __shfl_xor(mx, 32));

        float p[16], ls = 0.f;
        #pragma unroll
        for (int e = 0; e < 16; ++e) { p[e] = __expf(s[e] - mx); ls += p[e]; }
        ls += __shfl_xor(ls, 1);
        ls += __shfl_xor(ls, 2);
        ls += __shfl_xor(ls, 4);
        ls += __shfl_xor(ls, 8);
        ls += __shfl_xor(ls, 16);
        ls += __shfl_xor(ls, 32);
        const float inv = 1.0f / ls;

        if (j0 < limit) {
            bf16x8 o0, o1;
            #pragma unroll
            for (int e = 0; e < 8; ++e) {
                o0[e] = (short)f2bf(p[e] * inv);
                o1[e] = (short)f2bf(p[8 + e] * inv);
            }
            unsigned short* prow = P + ((size_t)(b * LL) + r) * LL;
            *(bf16x8*)(prow + j0)     = o0;
            *(bf16x8*)(prow + j0 + 8) = o1;
        }
    }
}

// ---------------------------------------------------------------------------
// Kernel 5: O = relu(P . V) via vt (unchanged).
// ---------------------------------------------------------------------------
__global__ __launch_bounds__(256, 2) void pv_gemm(
    const unsigned short* __restrict__ P,
    const unsigned short* __restrict__ vt,
    float* __restrict__ outp)
{
    __shared__ __align__(16) unsigned short At[2][8192];
    __shared__ __align__(16) unsigned short Bt[2][8192];

    int wg = blockIdx.x;
    wg = (wg & 7) * 128 + (wg >> 3);
    const int b  = wg >> 5;
    const int rr = wg & 31;
    const int rt = 7 - (rr >> 2);
    const int ct = rr & 3;

    const int tid  = threadIdx.x;
    const int lane = tid & 63;
    const int w    = tid >> 6;
    const int wr   = (w >> 1) * 64;
    const int wc   = (w & 1) * 64;
    const int l15  = lane & 15, l4 = lane >> 4;

    const int r8   = lane >> 3;
    const int swch = (lane & 7) ^ r8;

    const char* apanel = (const char*)(P  + ((size_t)(b * LL) + rt * 128) * LL);
    const char* bpanel = (const char*)(vt + ((size_t)(b * DD) + ct * 128) * LL);

    const int NT = (rt + 1) * 2;

    f32x4 acc[4][4];
    #pragma unroll
    for (int i = 0; i < 4; ++i)
        #pragma unroll
        for (int j = 0; j < 4; ++j)
            acc[i][j] = (f32x4){0.f, 0.f, 0.f, 0.f};

    #define STAGE_PV(KK, BUF) do {                                               \
        _Pragma("unroll")                                                        \
        for (int i2 = 0; i2 < 4; ++i2) {                                         \
            int grp = i2 * 4 + w;                                                \
            size_t rowoff = (size_t)(grp * 8 + r8) * 2048 + (KK) * 2 + swch * 16;\
            GLOAD_LDS16(apanel + rowoff, (char*)&At[BUF][0] + grp * 1024);       \
            GLOAD_LDS16(bpanel + rowoff, (char*)&Bt[BUF][0] + grp * 1024);       \
        }                                                                        \
    } while (0)

    STAGE_PV(0, 0);
    __syncthreads();

    for (int t = 0; t < NT; ++t) {
        const int cur = t & 1;
        if (t < NT - 1) STAGE_PV((t + 1) * 64, cur ^ 1);

        const char* Ab = (const char*)&At[cur][0];
        const char* Bb = (const char*)&Bt[cur][0];
        #pragma unroll
        for (int ks = 0; ks < 2; ++ks) {
            bf16x8 af[4], bf_[4];
            const int ch = (ks * 4 + l4) ^ (l15 & 7);
            #pragma unroll
            for (int m = 0; m < 4; ++m)
                af[m] = *(const bf16x8*)(Ab + (wr + m * 16 + l15) * 128 + (ch << 4));
            #pragma unroll
            for (int n = 0; n < 4; ++n)
                bf_[n] = *(const bf16x8*)(Bb + (wc + n * 16 + l15) * 128 + (ch << 4));
            #pragma unroll
            for (int n = 0; n < 4; ++n)
                #pragma unroll
                for (int m = 0; m < 4; ++m)
                    acc[m][n] = __builtin_amdgcn_mfma_f32_16x16x32_bf16(af[m], bf_[n], acc[m][n], 0, 0, 0);
        }

        if (t < NT - 1) publish_barrier();
    }
    #undef STAGE_PV

    float* op = outp + ((size_t)(b * LL) + rt * 128) * DD + ct * 128;
    #pragma unroll
    for (int n = 0; n < 4; ++n) {
        int col = wc + n * 16 + l15;
        #pragma unroll
        for (int m = 0; m < 4; ++m) {
            int row0 = wr + m * 16 + l4 * 4;
            #pragma unroll
            for (int r = 0; r < 4; ++r)
                op[(size_t)(row0 + r) * DD + col] = fmaxf(acc[m][n][r], 0.f);
        }
    }
}

extern "C" void kernel_launch(void* const* d_in, const int* in_sizes, int n_in,
                              void* d_out, int out_size, void* d_ws, size_t ws_size,
                              hipStream_t stream) {
    const float* x  = (const float*)d_in[0];
    const float* Wq = (const float*)d_in[1];
    const float* bq = (const float*)d_in[2];
    const float* Wk = (const float*)d_in[3];
    const float* bk = (const float*)d_in[4];
    const float* Wv = (const float*)d_in[5];
    const float* bv = (const float*)d_in[6];
    const int* mask = (const int*)d_in[7];

    unsigned short* qkv = (unsigned short*)d_ws;          // q | k (2 x 32MB)
    unsigned short* vtp = qkv + 2 * MAT;                  // vt [b][d][l] (32MB)
    unsigned short* Wb  = qkv + 3 * MAT;                  // W bf16 (3MB)
    unsigned short* xb  = (unsigned short*)d_out;         // x bf16 (64MB), dead after proj
    unsigned short* S   = (unsigned short*)d_out;         // S bf16 (64MB), overwrites xb
    unsigned short* Pp  = qkv;                            // P bf16 over q+k (dead)
    float* out = (float*)d_out;                           // final O overwrites S

    cast_all<<<17152, 256, 0, stream>>>(x, Wq, Wk, Wv, xb, Wb);
    qkv_proj8<<<dim3(256, 3), 512, 0, stream>>>(xb, Wb, bq, bk, bv, qkv, vtp);
    sgemm_qk<<<dim3(1152), 256, 0, stream>>>(qkv, S);
    softmax_rows<<<dim3(32, 32), 256, 0, stream>>>(S, mask, Pp);
    pv_gemm<<<dim3(1024), 256, 0, stream>>>(Pp, vtp, out);
}

// Round 16
// 243.297 us; speedup vs baseline: 1.1627x; 1.0225x over previous
//
#include <hip/hip_runtime.h>
#include <hip/hip_bf16.h>
#include <stdint.h>

#define DM 1024   // d_model
#define DD 512    // d (proj out / head dim)
#define BB 32     // batch
#define LL 1024   // seq len
#define SCALE 0.04419417382415922f  // 1/sqrt(512)
#define MAT ((size_t)BB * LL * DD)  // elems per q/k/v matrix

typedef float f32x4 __attribute__((ext_vector_type(4)));
typedef short bf16x8 __attribute__((ext_vector_type(8)));
typedef short bf16x4 __attribute__((ext_vector_type(4)));

__device__ inline unsigned short f2bf(float f) {
    union { float f; uint32_t u; } v; v.f = f;
    uint32_t r = v.u + 0x7fffu + ((v.u >> 16) & 1u);
    return (unsigned short)(r >> 16);
}
__device__ inline float bf2f(unsigned short u) {
    union { uint32_t u; float f; } v; v.u = ((uint32_t)u) << 16;
    return v.f;
}

__device__ inline bf16x4 cvt4(f32x4 a, float s) {
    bf16x4 r;
    r[0] = (short)f2bf(a[0] * s);
    r[1] = (short)f2bf(a[1] * s);
    r[2] = (short)f2bf(a[2] * s);
    r[3] = (short)f2bf(a[3] * s);
    return r;
}

#define GLOAD_LDS16(gsrc, ldst) \
    __builtin_amdgcn_global_load_lds((const __attribute__((address_space(1))) unsigned int*)(gsrc), \
        (__attribute__((address_space(3))) unsigned int*)(ldst), 16, 0, 0)

__device__ inline void publish_barrier() {
    asm volatile("s_waitcnt vmcnt(0)" ::: "memory");
    __builtin_amdgcn_sched_barrier(0);
    __builtin_amdgcn_s_barrier();
    __builtin_amdgcn_sched_barrier(0);
}
__device__ inline void gate4() {
    asm volatile("s_waitcnt vmcnt(4)" ::: "memory");
    __builtin_amdgcn_sched_barrier(0);
    __builtin_amdgcn_s_barrier();
    __builtin_amdgcn_sched_barrier(0);
}
__device__ inline void gate2() {
    asm volatile("s_waitcnt vmcnt(2)" ::: "memory");
    __builtin_amdgcn_sched_barrier(0);
    __builtin_amdgcn_s_barrier();
    __builtin_amdgcn_sched_barrier(0);
}
__device__ inline void gate0() {
    asm volatile("s_waitcnt vmcnt(0)" ::: "memory");
    __builtin_amdgcn_sched_barrier(0);
    __builtin_amdgcn_s_barrier();
    __builtin_amdgcn_sched_barrier(0);
}
__device__ inline void gateB() {
    __builtin_amdgcn_sched_barrier(0);
    __builtin_amdgcn_s_barrier();
    __builtin_amdgcn_sched_barrier(0);
}

// ---------------------------------------------------------------------------
// Kernel 0: fused casts. Blocks [0,16384): x fp32->bf16 into xb.
// Blocks [16384,17152): Wq/Wk/Wv fp32->bf16 (Wq pre-scaled) into Wb.
// ---------------------------------------------------------------------------
__global__ __launch_bounds__(256) void cast_all(const float* __restrict__ x,
                                                const float* __restrict__ Wq,
                                                const float* __restrict__ Wk,
                                                const float* __restrict__ Wv,
                                                unsigned short* __restrict__ xb,
                                                unsigned short* __restrict__ Wb)
{
    int bx = blockIdx.x;
    if (bx < 16384) {
        size_t idx = (size_t)bx * 256 + threadIdx.x;
        size_t base = idx * 8;
        f32x4 a = *(const f32x4*)(x + base);
        f32x4 b = *(const f32x4*)(x + base + 4);
        bf16x4 lo = cvt4(a, 1.0f), hi = cvt4(b, 1.0f);
        bf16x8 o = {lo[0], lo[1], lo[2], lo[3], hi[0], hi[1], hi[2], hi[3]};
        *(bf16x8*)(xb + base) = o;
    } else {
        size_t idx = (size_t)(bx - 16384) * 256 + threadIdx.x;  // 0..196607
        int o = (int)(idx >> 16);
        size_t rem = idx & 65535;
        const float* W = (o == 0) ? Wq : (o == 1) ? Wk : Wv;
        float s = (o == 0) ? SCALE : 1.0f;
        size_t base = rem * 8;
        f32x4 a = *(const f32x4*)(W + base);
        f32x4 b = *(const f32x4*)(W + base + 4);
        bf16x4 lo = cvt4(a, s), hi = cvt4(b, s);
        bf16x8 out = {lo[0], lo[1], lo[2], lo[3], hi[0], hi[1], hi[2], hi[3]};
        *(bf16x8*)(Wb + (size_t)o * 524288 + base) = out;
    }
}

// ---------------------------------------------------------------------------
// Kernel 1: q/k/v projection v6 (round-13 version, verbatim — 117.5 us;
// schedule FROZEN after 4 null/negative probes: setprio-lockstep, frag
// pipelining, fp32-x fusion, m201 trailing-barrier+setprio).
// V output (o==2): LDS-transpose epilogue -> vt[b][d][l].
// ---------------------------------------------------------------------------
__global__ __launch_bounds__(512, 2) void qkv_proj6(
    const unsigned short* __restrict__ xb,
    const unsigned short* __restrict__ Wb,
    const float* __restrict__ bq, const float* __restrict__ bk, const float* __restrict__ bv,
    unsigned short* __restrict__ qkv,     // q at 0, k at MAT
    unsigned short* __restrict__ vt)      // [b][d][l]
{
    __shared__ __align__(16) unsigned short AL[2][2][8192];
    __shared__ __align__(16) unsigned short BL[2][2][8192];

    const int o = blockIdx.y;
    const float* bias = (o == 0) ? bq : (o == 1) ? bk : bv;
    const float wscale = (o == 0) ? SCALE : 1.0f;
    const unsigned short* W = Wb + (size_t)o * 524288;
    unsigned short* out = qkv + (size_t)o * MAT;

    int wg = blockIdx.x;
    wg = (wg & 7) * 32 + (wg >> 3);
    const int mt = wg >> 1, nt = wg & 1;
    const int rowbase = mt * 256;
    const int colbase = nt * 256;

    const int tid  = threadIdx.x;
    const int lane = tid & 63;
    const int w    = tid >> 6;
    const int wm   = w >> 2;
    const int wn   = w & 3;
    const int l15  = lane & 15, l4 = lane >> 4;
    const int rxor = l15 & 7;

    const int r8   = lane >> 3;
    const int swch = (lane & 7) ^ r8;

    const char* xpanel = (const char*)(xb + (size_t)rowbase * DM);
    const char* wpanel = (const char*)(W  + (size_t)colbase * DM);

    #define STAGE_HALF(panel, T, H, slot) do {                                   \
        _Pragma("unroll")                                                        \
        for (int i2 = 0; i2 < 2; ++i2) {                                         \
            int grp = i2 * 8 + w;                                                \
            GLOAD_LDS16((panel) + ((size_t)((H) * 128 + grp * 8 + r8) * 2048)    \
                            + (size_t)(T) * 128 + swch * 16,                     \
                        (char*)(slot) + grp * 1024);                             \
        }                                                                        \
    } while (0)

    #define RDA(base, mf4, ks) (*(const bf16x8*)((base) + (wm * 64 + (mf4) * 16 + l15) * 128 \
                            + ((((ks) * 4 + l4) ^ rxor) << 4)))
    #define RDB(base, nfl, ks) (*(const bf16x8*)((base) + (wn * 32 + (nfl) * 16 + l15) * 128 \
                            + ((((ks) * 4 + l4) ^ rxor) << 4)))

    f32x4 acc[8][4];
    #pragma unroll
    for (int i = 0; i < 8; ++i)
        #pragma unroll
        for (int j = 0; j < 4; ++j)
            acc[i][j] = (f32x4){0.f, 0.f, 0.f, 0.f};

    bf16x8 aF[4][2], bF[4][2];

    STAGE_HALF(xpanel, 0, 0, &AL[0][0][0]);   // A0
    STAGE_HALF(wpanel, 0, 0, &BL[0][0][0]);   // B0
    STAGE_HALF(wpanel, 0, 1, &BL[0][1][0]);   // B1
    STAGE_HALF(xpanel, 0, 1, &AL[0][1][0]);   // A1

    for (int t = 0; t < 16; ++t) {
        const int c = t & 1, cn = c ^ 1;
        const char* A0b = (const char*)&AL[c][0][0];
        const char* A1b = (const char*)&AL[c][1][0];
        const char* B0b = (const char*)&BL[c][0][0];
        const char* B1b = (const char*)&BL[c][1][0];
        const bool st = (t < 15);

        // ---- phase 0: (A0,B0) ----
        if (st) { STAGE_HALF(xpanel, t + 1, 0, &AL[cn][0][0]); gate4(); } else gate2();
        #pragma unroll
        for (int ks = 0; ks < 2; ++ks) {
            #pragma unroll
            for (int mf = 0; mf < 4; ++mf) aF[mf][ks] = RDA(A0b, mf, ks);
            bF[0][ks] = RDB(B0b, 0, ks);
            bF[1][ks] = RDB(B0b, 1, ks);
        }
        #pragma unroll
        for (int ks = 0; ks < 2; ++ks) {          // prefetch B1 frags (used in Q1)
            bF[2][ks] = RDB(B1b, 0, ks);
            bF[3][ks] = RDB(B1b, 1, ks);
        }
        #pragma unroll
        for (int ks = 0; ks < 2; ++ks)
            #pragma unroll
            for (int nf = 0; nf < 2; ++nf)
                #pragma unroll
                for (int mf = 0; mf < 4; ++mf)
                    acc[mf][nf] = __builtin_amdgcn_mfma_f32_16x16x32_bf16(aF[mf][ks], bF[nf][ks], acc[mf][nf], 0, 0, 0);

        // ---- phase 1: (A0,B1) ----
        if (st) { STAGE_HALF(wpanel, t + 1, 0, &BL[cn][0][0]); gate4(); } else gate0();
        #pragma unroll
        for (int ks = 0; ks < 2; ++ks)
            #pragma unroll
            for (int nf = 0; nf < 2; ++nf)
                #pragma unroll
                for (int mf = 0; mf < 4; ++mf)
                    acc[mf][2 + nf] = __builtin_amdgcn_mfma_f32_16x16x32_bf16(aF[mf][ks], bF[2 + nf][ks], acc[mf][2 + nf], 0, 0, 0);
        #pragma unroll
        for (int ks = 0; ks < 2; ++ks)            // back-load A1 frags (Q2/Q3)
            #pragma unroll
            for (int mf = 0; mf < 4; ++mf) aF[mf][ks] = RDA(A1b, mf, ks);

        // ---- phase 2: (A1,B0) — regs only ----
        if (st) STAGE_HALF(wpanel, t + 1, 1, &BL[cn][1][0]);
        gateB();
        #pragma unroll
        for (int ks = 0; ks < 2; ++ks)
            #pragma unroll
            for (int nf = 0; nf < 2; ++nf)
                #pragma unroll
                for (int mf = 0; mf < 4; ++mf)
                    acc[4 + mf][nf] = __builtin_amdgcn_mfma_f32_16x16x32_bf16(aF[mf][ks], bF[nf][ks], acc[4 + mf][nf], 0, 0, 0);

        // ---- phase 3: (A1,B1) — regs only ----
        if (st) STAGE_HALF(xpanel, t + 1, 1, &AL[cn][1][0]);
        gateB();
        #pragma unroll
        for (int ks = 0; ks < 2; ++ks)
            #pragma unroll
            for (int nf = 0; nf < 2; ++nf)
                #pragma unroll
                for (int mf = 0; mf < 4; ++mf)
                    acc[4 + mf][2 + nf] = __builtin_amdgcn_mfma_f32_16x16x32_bf16(aF[mf][ks], bF[2 + nf][ks], acc[4 + mf][2 + nf], 0, 0, 0);
    }
    #undef STAGE_HALF
    #undef RDA
    #undef RDB

    if (o != 2) {
        #pragma unroll
        for (int nf = 0; nf < 4; ++nf) {
            int col = colbase + ((nf < 2) ? wn * 32 + nf * 16 : 128 + wn * 32 + (nf - 2) * 16) + l15;
            float bv_ = bias[col] * wscale;
            #pragma unroll
            for (int mf = 0; mf < 8; ++mf) {
                int row0 = rowbase + ((mf < 4) ? wm * 64 + mf * 16 : 128 + wm * 64 + (mf - 4) * 16) + l4 * 4;
                #pragma unroll
                for (int r = 0; r < 4; ++r)
                    out[(size_t)(row0 + r) * DD + col] = f2bf(acc[mf][nf][r] + bv_);
            }
        }
    } else {
        // ---- V epilogue: transpose 256x256 tile via LDS -> vt[b][d][l] ----
        unsigned short* ldsT = (unsigned short*)&AL[0][0][0];
        const int bidx  = rowbase >> 10;
        const int lbase = rowbase & 1023;
        #pragma unroll
        for (int p = 0; p < 4; ++p) {
            __syncthreads();
            #pragma unroll
            for (int nf = 0; nf < 4; ++nf) {
                int base16 = (nf < 2) ? wn * 32 + nf * 16 : 128 + wn * 32 + (nf - 2) * 16;
                if (base16 >= p * 64 && base16 < p * 64 + 64) {
                    int cc = base16 - p * 64 + l15;
                    float bv_ = bias[colbase + base16 + l15];
                    #pragma unroll
                    for (int mf = 0; mf < 8; ++mf) {
                        int rowl = ((mf < 4) ? wm * 64 + mf * 16 : 128 + wm * 64 + (mf - 4) * 16) + l4 * 4;
                        bf16x4 v4;
                        #pragma unroll
                        for (int r = 0; r < 4; ++r)
                            v4[r] = (short)f2bf(acc[mf][nf][r] + bv_);
                        *(bf16x4*)&ldsT[cc * 264 + rowl] = v4;
                    }
                }
            }
            __syncthreads();
            #pragma unroll
            for (int it = 0; it < 4; ++it) {
                int uu = tid + it * 512;
                int cc = uu >> 5;
                int r0 = (uu & 31) * 8;
                bf16x8 val = *(const bf16x8*)&ldsT[cc * 264 + r0];
                int dg = colbase + p * 64 + cc;
                *(bf16x8*)(vt + ((size_t)(bidx * DD + dg)) * LL + lbase + r0) = val;
            }
        }
    }
}

// ---------------------------------------------------------------------------
// Kernel 3: S = q . k^T, lower-triangle 128x128 tiles (unchanged).
// ---------------------------------------------------------------------------
__global__ __launch_bounds__(256, 2) void sgemm_qk(
    const unsigned short* __restrict__ qkv,
    unsigned short* __restrict__ S)
{
    __shared__ __align__(16) unsigned short At[2][8192];
    __shared__ __align__(16) unsigned short Bt[2][8192];

    int wg = blockIdx.x;
    wg = (wg & 7) * 144 + (wg >> 3);
    const int b = wg / 36;
    const int t36 = wg % 36;
    int mt = 0, accq = 0;
    while (accq + mt + 1 <= t36) { ++mt; accq += mt; }
    const int nt = t36 - accq;

    const int tid  = threadIdx.x;
    const int lane = tid & 63;
    const int w    = tid >> 6;
    const int wr   = (w >> 1) * 64;
    const int wc   = (w & 1) * 64;
    const int l15  = lane & 15, l4 = lane >> 4;

    const int r8   = lane >> 3;
    const int swch = (lane & 7) ^ r8;

    const unsigned short* q = qkv;
    const unsigned short* k = qkv + MAT;
    const char* apanel = (const char*)(q + ((size_t)(b * LL) + mt * 128) * DD);
    const char* bpanel = (const char*)(k + ((size_t)(b * LL) + nt * 128) * DD);

    f32x4 acc[4][4];
    #pragma unroll
    for (int i = 0; i < 4; ++i)
        #pragma unroll
        for (int j = 0; j < 4; ++j)
            acc[i][j] = (f32x4){0.f, 0.f, 0.f, 0.f};

    #define STAGE_QK(KK, BUF) do {                                               \
        _Pragma("unroll")                                                        \
        for (int i2 = 0; i2 < 4; ++i2) {                                         \
            int grp = i2 * 4 + w;                                                \
            size_t rowoff = (size_t)(grp * 8 + r8) * 1024 + (KK) * 2 + swch * 16;\
            GLOAD_LDS16(apanel + rowoff, (char*)&At[BUF][0] + grp * 1024);       \
            GLOAD_LDS16(bpanel + rowoff, (char*)&Bt[BUF][0] + grp * 1024);       \
        }                                                                        \
    } while (0)

    STAGE_QK(0, 0);
    __syncthreads();

    for (int t = 0; t < 8; ++t) {
        const int cur = t & 1;
        if (t < 7) STAGE_QK((t + 1) * 64, cur ^ 1);

        const char* Ab = (const char*)&At[cur][0];
        const char* Bb = (const char*)&Bt[cur][0];
        #pragma unroll
        for (int ks = 0; ks < 2; ++ks) {
            bf16x8 af[4], bf_[4];
            const int ch = (ks * 4 + l4) ^ (l15 & 7);
            #pragma unroll
            for (int m = 0; m < 4; ++m)
                af[m] = *(const bf16x8*)(Ab + (wr + m * 16 + l15) * 128 + (ch << 4));
            #pragma unroll
            for (int n = 0; n < 4; ++n)
                bf_[n] = *(const bf16x8*)(Bb + (wc + n * 16 + l15) * 128 + (ch << 4));
            #pragma unroll
            for (int n = 0; n < 4; ++n)
                #pragma unroll
                for (int m = 0; m < 4; ++m)
                    acc[m][n] = __builtin_amdgcn_mfma_f32_16x16x32_bf16(af[m], bf_[n], acc[m][n], 0, 0, 0);
        }

        if (t < 7) publish_barrier();
    }
    #undef STAGE_QK

    unsigned short* sp = S + ((size_t)(b * LL) + mt * 128) * LL + nt * 128;
    #pragma unroll
    for (int n = 0; n < 4; ++n) {
        int col = wc + n * 16 + l15;
        #pragma unroll
        for (int m = 0; m < 4; ++m) {
            int row0 = wr + m * 16 + l4 * 4;
            #pragma unroll
            for (int r = 0; r < 4; ++r)
                sp[(size_t)(row0 + r) * LL + col] = f2bf(acc[m][n][r]);
        }
    }
}

// ---------------------------------------------------------------------------
// Kernel 4: row softmax v2 (unchanged from round 13).
// ---------------------------------------------------------------------------
__global__ __launch_bounds__(256) void softmax_rows(
    const unsigned short* __restrict__ S,
    const int* __restrict__ mask,
    unsigned short* __restrict__ P)
{
    __shared__ float mbias[1024];
    const int rc = blockIdx.x, b = blockIdx.y;
    const int tid = threadIdx.x, lane = tid & 63, w = tid >> 6;

    {
        const int* mp = mask + b * LL;
        #pragma unroll
        for (int j = 0; j < 4; ++j)
            mbias[tid * 4 + j] = mp[tid * 4 + j] ? 0.0f : -1e30f;
    }
    __syncthreads();

    const int j0 = lane * 16;
    const int limit = ((rc >> 2) + 1) << 7;
    for (int i = 0; i < 8; ++i) {
        const int r = rc * 32 + i * 4 + w;
        const unsigned short* srow = S + ((size_t)(b * LL) + r) * LL;

        bf16x8 v0 = {0,0,0,0,0,0,0,0}, v1 = {0,0,0,0,0,0,0,0};
        if (j0 <= r)     v0 = *(const bf16x8*)(srow + j0);
        if (j0 + 8 <= r) v1 = *(const bf16x8*)(srow + j0 + 8);

        float s[16];
        #pragma unroll
        for (int e = 0; e < 8; ++e) {
            int j = j0 + e;
            s[e]     = (j <= r)     ? bf2f((unsigned short)v0[e]) + mbias[j]     : -3e38f;
            s[8 + e] = (j + 8 <= r) ? bf2f((unsigned short)v1[e]) + mbias[j + 8] : -3e38f;
        }
        float mx = s[0];
        #pragma unroll
        for (int e = 1; e < 16; ++e) mx = fmaxf(mx, s[e]);
        mx = fmaxf(mx, __shfl_xor(mx, 1));
        mx = fmaxf(mx, __shfl_xor(mx, 2));
        mx = fmaxf(mx, __shfl_xor(mx, 4));
        mx = fmaxf(mx, __shfl_xor(mx, 8));
        mx = fmaxf(mx, __shfl_xor(mx, 16));
        mx = fmaxf(mx, __shfl_xor(mx, 32));

        float p[16], ls = 0.f;
        #pragma unroll
        for (int e = 0; e < 16; ++e) { p[e] = __expf(s[e] - mx); ls += p[e]; }
        ls += __shfl_xor(ls, 1);
        ls += __shfl_xor(ls, 2);
        ls += __shfl_xor(ls, 4);
        ls += __shfl_xor(ls, 8);
        ls += __shfl_xor(ls, 16);
        ls += __shfl_xor(ls, 32);
        const float inv = 1.0f / ls;

        if (j0 < limit) {
            bf16x8 o0, o1;
            #pragma unroll
            for (int e = 0; e < 8; ++e) {
                o0[e] = (short)f2bf(p[e] * inv);
                o1[e] = (short)f2bf(p[8 + e] * inv);
            }
            unsigned short* prow = P + ((size_t)(b * LL) + r) * LL;
            *(bf16x8*)(prow + j0)     = o0;
            *(bf16x8*)(prow + j0 + 8) = o1;
        }
    }
}

// ---------------------------------------------------------------------------
// Kernel 5: O = relu(P . V) via vt. CHANGE: heavy/light interleaved dispatch
// order (rt sequence 7,0,6,1,5,2,4,3 per 4-block group) so every dispatch
// window averages NT~9 instead of heavy-first's 13-then-5 rounds.
// ---------------------------------------------------------------------------
__global__ __launch_bounds__(256, 2) void pv_gemm(
    const unsigned short* __restrict__ P,
    const unsigned short* __restrict__ vt,
    float* __restrict__ outp)
{
    __shared__ __align__(16) unsigned short At[2][8192];
    __shared__ __align__(16) unsigned short Bt[2][8192];

    int wg = blockIdx.x;
    wg = (wg & 7) * 128 + (wg >> 3);
    const int b  = wg >> 5;
    const int rr = wg & 31;
    const int idx = rr >> 2;
    const int rt = (idx & 1) ? ((idx - 1) >> 1) : (7 - (idx >> 1));  // 7,0,6,1,5,2,4,3
    const int ct = rr & 3;

    const int tid  = threadIdx.x;
    const int lane = tid & 63;
    const int w    = tid >> 6;
    const int wr   = (w >> 1) * 64;
    const int wc   = (w & 1) * 64;
    const int l15  = lane & 15, l4 = lane >> 4;

    const int r8   = lane >> 3;
    const int swch = (lane & 7) ^ r8;

    const char* apanel = (const char*)(P  + ((size_t)(b * LL) + rt * 128) * LL);
    const char* bpanel = (const char*)(vt + ((size_t)(b * DD) + ct * 128) * LL);

    const int NT = (rt + 1) * 2;

    f32x4 acc[4][4];
    #pragma unroll
    for (int i = 0; i < 4; ++i)
        #pragma unroll
        for (int j = 0; j < 4; ++j)
            acc[i][j] = (f32x4){0.f, 0.f, 0.f, 0.f};

    #define STAGE_PV(KK, BUF) do {                                               \
        _Pragma("unroll")                                                        \
        for (int i2 = 0; i2 < 4; ++i2) {                                         \
            int grp = i2 * 4 + w;                                                \
            size_t rowoff = (size_t)(grp * 8 + r8) * 2048 + (KK) * 2 + swch * 16;\
            GLOAD_LDS16(apanel + rowoff, (char*)&At[BUF][0] + grp * 1024);       \
            GLOAD_LDS16(bpanel + rowoff, (char*)&Bt[BUF][0] + grp * 1024);       \
        }                                                                        \
    } while (0)

    STAGE_PV(0, 0);
    __syncthreads();

    for (int t = 0; t < NT; ++t) {
        const int cur = t & 1;
        if (t < NT - 1) STAGE_PV((t + 1) * 64, cur ^ 1);

        const char* Ab = (const char*)&At[cur][0];
        const char* Bb = (const char*)&Bt[cur][0];
        #pragma unroll
        for (int ks = 0; ks < 2; ++ks) {
            bf16x8 af[4], bf_[4];
            const int ch = (ks * 4 + l4) ^ (l15 & 7);
            #pragma unroll
            for (int m = 0; m < 4; ++m)
                af[m] = *(const bf16x8*)(Ab + (wr + m * 16 + l15) * 128 + (ch << 4));
            #pragma unroll
            for (int n = 0; n < 4; ++n)
                bf_[n] = *(const bf16x8*)(Bb + (wc + n * 16 + l15) * 128 + (ch << 4));
            #pragma unroll
            for (int n = 0; n < 4; ++n)
                #pragma unroll
                for (int m = 0; m < 4; ++m)
                    acc[m][n] = __builtin_amdgcn_mfma_f32_16x16x32_bf16(af[m], bf_[n], acc[m][n], 0, 0, 0);
        }

        if (t < NT - 1) publish_barrier();
    }
    #undef STAGE_PV

    float* op = outp + ((size_t)(b * LL) + rt * 128) * DD + ct * 128;
    #pragma unroll
    for (int n = 0; n < 4; ++n) {
        int col = wc + n * 16 + l15;
        #pragma unroll
        for (int m = 0; m < 4; ++m) {
            int row0 = wr + m * 16 + l4 * 4;
            #pragma unroll
            for (int r = 0; r < 4; ++r)
                op[(size_t)(row0 + r) * DD + col] = fmaxf(acc[m][n][r], 0.f);
        }
    }
}

extern "C" void kernel_launch(void* const* d_in, const int* in_sizes, int n_in,
                              void* d_out, int out_size, void* d_ws, size_t ws_size,
                              hipStream_t stream) {
    const float* x  = (const float*)d_in[0];
    const float* Wq = (const float*)d_in[1];
    const float* bq = (const float*)d_in[2];
    const float* Wk = (const float*)d_in[3];
    const float* bk = (const float*)d_in[4];
    const float* Wv = (const float*)d_in[5];
    const float* bv = (const float*)d_in[6];
    const int* mask = (const int*)d_in[7];

    unsigned short* qkv = (unsigned short*)d_ws;          // q | k (2 x 32MB)
    unsigned short* vtp = qkv + 2 * MAT;                  // vt [b][d][l] (32MB)
    unsigned short* Wb  = qkv + 3 * MAT;                  // W bf16 (3MB)
    unsigned short* xb  = (unsigned short*)d_out;         // x bf16 (64MB), dead after proj
    unsigned short* S   = (unsigned short*)d_out;         // S bf16 (64MB), overwrites xb
    unsigned short* Pp  = qkv;                            // P bf16 over q+k (dead)
    float* out = (float*)d_out;                           // final O overwrites S

    cast_all<<<17152, 256, 0, stream>>>(x, Wq, Wk, Wv, xb, Wb);
    qkv_proj6<<<dim3(256, 3), 512, 0, stream>>>(xb, Wb, bq, bk, bv, qkv, vtp);
    sgemm_qk<<<dim3(1152), 256, 0, stream>>>(qkv, S);
    softmax_rows<<<dim3(32, 32), 256, 0, stream>>>(S, mask, Pp);
    pv_gemm<<<dim3(1024), 256, 0, stream>>>(Pp, vtp, out);
}

// Round 17
// 239.324 us; speedup vs baseline: 1.1820x; 1.0166x over previous
//
#include <hip/hip_runtime.h>
#include <hip/hip_bf16.h>
#include <stdint.h>

#define DM 1024   // d_model
#define DD 512    // d (proj out / head dim)
#define BB 32     // batch
#define LL 1024   // seq len
#define SCALE 0.04419417382415922f  // 1/sqrt(512)
#define MAT ((size_t)BB * LL * DD)  // elems per q/k/v matrix

typedef float f32x4 __attribute__((ext_vector_type(4)));
typedef short bf16x8 __attribute__((ext_vector_type(8)));
typedef short bf16x4 __attribute__((ext_vector_type(4)));

__device__ inline unsigned short f2bf(float f) {
    union { float f; uint32_t u; } v; v.f = f;
    uint32_t r = v.u + 0x7fffu + ((v.u >> 16) & 1u);
    return (unsigned short)(r >> 16);
}
__device__ inline float bf2f(unsigned short u) {
    union { uint32_t u; float f; } v; v.u = ((uint32_t)u) << 16;
    return v.f;
}

__device__ inline bf16x4 cvt4(f32x4 a, float s) {
    bf16x4 r;
    r[0] = (short)f2bf(a[0] * s);
    r[1] = (short)f2bf(a[1] * s);
    r[2] = (short)f2bf(a[2] * s);
    r[3] = (short)f2bf(a[3] * s);
    return r;
}

#define GLOAD_LDS16(gsrc, ldst) \
    __builtin_amdgcn_global_load_lds((const __attribute__((address_space(1))) unsigned int*)(gsrc), \
        (__attribute__((address_space(3))) unsigned int*)(ldst), 16, 0, 0)

__device__ inline void publish_barrier() {
    asm volatile("s_waitcnt vmcnt(0)" ::: "memory");
    __builtin_amdgcn_sched_barrier(0);
    __builtin_amdgcn_s_barrier();
    __builtin_amdgcn_sched_barrier(0);
}
__device__ inline void gate4() {
    asm volatile("s_waitcnt vmcnt(4)" ::: "memory");
    __builtin_amdgcn_sched_barrier(0);
    __builtin_amdgcn_s_barrier();
    __builtin_amdgcn_sched_barrier(0);
}
__device__ inline void gate2() {
    asm volatile("s_waitcnt vmcnt(2)" ::: "memory");
    __builtin_amdgcn_sched_barrier(0);
    __builtin_amdgcn_s_barrier();
    __builtin_amdgcn_sched_barrier(0);
}
__device__ inline void gate0() {
    asm volatile("s_waitcnt vmcnt(0)" ::: "memory");
    __builtin_amdgcn_sched_barrier(0);
    __builtin_amdgcn_s_barrier();
    __builtin_amdgcn_sched_barrier(0);
}
__device__ inline void gateB() {
    __builtin_amdgcn_sched_barrier(0);
    __builtin_amdgcn_s_barrier();
    __builtin_amdgcn_sched_barrier(0);
}

// ---------------------------------------------------------------------------
// Kernel 0: fused casts, grid-stride over 2048 blocks (G11: cap grid, stride
// the rest — removes ~15K block-dispatch overhead on a pure-BW kernel).
// Chunks [0,4194304): x fp32->bf16. Chunks [4194304,4390912): W (q scaled).
// ---------------------------------------------------------------------------
#define NCHUNK (16384 * 256 + 768 * 256)
__global__ __launch_bounds__(256) void cast_all(const float* __restrict__ x,
                                                const float* __restrict__ Wq,
                                                const float* __restrict__ Wk,
                                                const float* __restrict__ Wv,
                                                unsigned short* __restrict__ xb,
                                                unsigned short* __restrict__ Wb)
{
    for (size_t idx = (size_t)blockIdx.x * 256 + threadIdx.x; idx < NCHUNK;
         idx += (size_t)2048 * 256) {
        if (idx < (size_t)16384 * 256) {
            size_t base = idx * 8;
            f32x4 a = *(const f32x4*)(x + base);
            f32x4 b = *(const f32x4*)(x + base + 4);
            bf16x4 lo = cvt4(a, 1.0f), hi = cvt4(b, 1.0f);
            bf16x8 o = {lo[0], lo[1], lo[2], lo[3], hi[0], hi[1], hi[2], hi[3]};
            *(bf16x8*)(xb + base) = o;
        } else {
            size_t wi = idx - (size_t)16384 * 256;   // 0..196607
            int o = (int)(wi >> 16);
            size_t rem = wi & 65535;
            const float* W = (o == 0) ? Wq : (o == 1) ? Wk : Wv;
            float s = (o == 0) ? SCALE : 1.0f;
            size_t base = rem * 8;
            f32x4 a = *(const f32x4*)(W + base);
            f32x4 b = *(const f32x4*)(W + base + 4);
            bf16x4 lo = cvt4(a, s), hi = cvt4(b, s);
            bf16x8 out = {lo[0], lo[1], lo[2], lo[3], hi[0], hi[1], hi[2], hi[3]};
            *(bf16x8*)(Wb + (size_t)o * 524288 + base) = out;
        }
    }
}

// ---------------------------------------------------------------------------
// Kernel 1: q/k/v projection v6b — r13's proj6 with P2+P3 MERGED into one
// phase (stage B1(t+1)+A1(t+1) together -> single barrier -> Q2+Q3 as one
// 32-MFMA reg-fed burst). Barriers/tile 4->3. Ledger (2 loads per stage):
//  gate4@P0(t): in-flight {B0(t),B1(t)+A1(t),A0(t+1)}=8 -> pops 6 =
//              A0(t)~already landed, B0(t), B1(t); leaves A1(t)+A0(t+1).
//              P0 reads A0,B0 frags + B1 prefetch: all covered.
//  gate4@P1(t): in-flight {A1(t),A0(t+1),B0(t+1)}=6 -> pops A1(t);
//              covers the A1 backload after Q1.
//  gateB@P23:  Q2+Q3 pure-register.
//  Tail (t=15): gate2@P0 (pops B0,B1; leaves A1), gate0@P1 (drains A1).
// WAR: every buffer overwrite separated from last read by >=1 barrier.
// V output (o==2): LDS-transpose epilogue -> vt[b][d][l].
// ---------------------------------------------------------------------------
__global__ __launch_bounds__(512, 2) void qkv_proj6b(
    const unsigned short* __restrict__ xb,
    const unsigned short* __restrict__ Wb,
    const float* __restrict__ bq, const float* __restrict__ bk, const float* __restrict__ bv,
    unsigned short* __restrict__ qkv,     // q at 0, k at MAT
    unsigned short* __restrict__ vt)      // [b][d][l]
{
    __shared__ __align__(16) unsigned short AL[2][2][8192];
    __shared__ __align__(16) unsigned short BL[2][2][8192];

    const int o = blockIdx.y;
    const float* bias = (o == 0) ? bq : (o == 1) ? bk : bv;
    const float wscale = (o == 0) ? SCALE : 1.0f;
    const unsigned short* W = Wb + (size_t)o * 524288;
    unsigned short* out = qkv + (size_t)o * MAT;

    int wg = blockIdx.x;
    wg = (wg & 7) * 32 + (wg >> 3);
    const int mt = wg >> 1, nt = wg & 1;
    const int rowbase = mt * 256;
    const int colbase = nt * 256;

    const int tid  = threadIdx.x;
    const int lane = tid & 63;
    const int w    = tid >> 6;
    const int wm   = w >> 2;
    const int wn   = w & 3;
    const int l15  = lane & 15, l4 = lane >> 4;
    const int rxor = l15 & 7;

    const int r8   = lane >> 3;
    const int swch = (lane & 7) ^ r8;

    const char* xpanel = (const char*)(xb + (size_t)rowbase * DM);
    const char* wpanel = (const char*)(W  + (size_t)colbase * DM);

    #define STAGE_HALF(panel, T, H, slot) do {                                   \
        _Pragma("unroll")                                                        \
        for (int i2 = 0; i2 < 2; ++i2) {                                         \
            int grp = i2 * 8 + w;                                                \
            GLOAD_LDS16((panel) + ((size_t)((H) * 128 + grp * 8 + r8) * 2048)    \
                            + (size_t)(T) * 128 + swch * 16,                     \
                        (char*)(slot) + grp * 1024);                             \
        }                                                                        \
    } while (0)

    #define RDA(base, mf4, ks) (*(const bf16x8*)((base) + (wm * 64 + (mf4) * 16 + l15) * 128 \
                            + ((((ks) * 4 + l4) ^ rxor) << 4)))
    #define RDB(base, nfl, ks) (*(const bf16x8*)((base) + (wn * 32 + (nfl) * 16 + l15) * 128 \
                            + ((((ks) * 4 + l4) ^ rxor) << 4)))

    f32x4 acc[8][4];
    #pragma unroll
    for (int i = 0; i < 8; ++i)
        #pragma unroll
        for (int j = 0; j < 4; ++j)
            acc[i][j] = (f32x4){0.f, 0.f, 0.f, 0.f};

    bf16x8 aF[4][2], bF[4][2];

    STAGE_HALF(xpanel, 0, 0, &AL[0][0][0]);   // A0
    STAGE_HALF(wpanel, 0, 0, &BL[0][0][0]);   // B0
    STAGE_HALF(wpanel, 0, 1, &BL[0][1][0]);   // B1
    STAGE_HALF(xpanel, 0, 1, &AL[0][1][0]);   // A1

    for (int t = 0; t < 16; ++t) {
        const int c = t & 1, cn = c ^ 1;
        const char* A0b = (const char*)&AL[c][0][0];
        const char* A1b = (const char*)&AL[c][1][0];
        const char* B0b = (const char*)&BL[c][0][0];
        const char* B1b = (const char*)&BL[c][1][0];
        const bool st = (t < 15);

        // ---- phase 0: (A0,B0) ----
        if (st) { STAGE_HALF(xpanel, t + 1, 0, &AL[cn][0][0]); gate4(); } else gate2();
        #pragma unroll
        for (int ks = 0; ks < 2; ++ks) {
            #pragma unroll
            for (int mf = 0; mf < 4; ++mf) aF[mf][ks] = RDA(A0b, mf, ks);
            bF[0][ks] = RDB(B0b, 0, ks);
            bF[1][ks] = RDB(B0b, 1, ks);
        }
        #pragma unroll
        for (int ks = 0; ks < 2; ++ks) {          // prefetch B1 frags (used in Q1/Q3)
            bF[2][ks] = RDB(B1b, 0, ks);
            bF[3][ks] = RDB(B1b, 1, ks);
        }
        #pragma unroll
        for (int ks = 0; ks < 2; ++ks)
            #pragma unroll
            for (int nf = 0; nf < 2; ++nf)
                #pragma unroll
                for (int mf = 0; mf < 4; ++mf)
                    acc[mf][nf] = __builtin_amdgcn_mfma_f32_16x16x32_bf16(aF[mf][ks], bF[nf][ks], acc[mf][nf], 0, 0, 0);

        // ---- phase 1: (A0,B1) ----
        if (st) { STAGE_HALF(wpanel, t + 1, 0, &BL[cn][0][0]); gate4(); } else gate0();
        #pragma unroll
        for (int ks = 0; ks < 2; ++ks)
            #pragma unroll
            for (int nf = 0; nf < 2; ++nf)
                #pragma unroll
                for (int mf = 0; mf < 4; ++mf)
                    acc[mf][2 + nf] = __builtin_amdgcn_mfma_f32_16x16x32_bf16(aF[mf][ks], bF[2 + nf][ks], acc[mf][2 + nf], 0, 0, 0);
        #pragma unroll
        for (int ks = 0; ks < 2; ++ks)            // back-load A1 frags (Q2/Q3)
            #pragma unroll
            for (int mf = 0; mf < 4; ++mf) aF[mf][ks] = RDA(A1b, mf, ks);

        // ---- phase 2+3 merged: (A1,B0) then (A1,B1) — one barrier, 32 MFMA ----
        if (st) {
            STAGE_HALF(wpanel, t + 1, 1, &BL[cn][1][0]);
            STAGE_HALF(xpanel, t + 1, 1, &AL[cn][1][0]);
        }
        gateB();
        #pragma unroll
        for (int ks = 0; ks < 2; ++ks)
            #pragma unroll
            for (int nf = 0; nf < 2; ++nf)
                #pragma unroll
                for (int mf = 0; mf < 4; ++mf)
                    acc[4 + mf][nf] = __builtin_amdgcn_mfma_f32_16x16x32_bf16(aF[mf][ks], bF[nf][ks], acc[4 + mf][nf], 0, 0, 0);
        #pragma unroll
        for (int ks = 0; ks < 2; ++ks)
            #pragma unroll
            for (int nf = 0; nf < 2; ++nf)
                #pragma unroll
                for (int mf = 0; mf < 4; ++mf)
                    acc[4 + mf][2 + nf] = __builtin_amdgcn_mfma_f32_16x16x32_bf16(aF[mf][ks], bF[2 + nf][ks], acc[4 + mf][2 + nf], 0, 0, 0);
    }
    #undef STAGE_HALF
    #undef RDA
    #undef RDB

    if (o != 2) {
        #pragma unroll
        for (int nf = 0; nf < 4; ++nf) {
            int col = colbase + ((nf < 2) ? wn * 32 + nf * 16 : 128 + wn * 32 + (nf - 2) * 16) + l15;
            float bv_ = bias[col] * wscale;
            #pragma unroll
            for (int mf = 0; mf < 8; ++mf) {
                int row0 = rowbase + ((mf < 4) ? wm * 64 + mf * 16 : 128 + wm * 64 + (mf - 4) * 16) + l4 * 4;
                #pragma unroll
                for (int r = 0; r < 4; ++r)
                    out[(size_t)(row0 + r) * DD + col] = f2bf(acc[mf][nf][r] + bv_);
            }
        }
    } else {
        // ---- V epilogue: transpose 256x256 tile via LDS -> vt[b][d][l] ----
        unsigned short* ldsT = (unsigned short*)&AL[0][0][0];
        const int bidx  = rowbase >> 10;
        const int lbase = rowbase & 1023;
        #pragma unroll
        for (int p = 0; p < 4; ++p) {
            __syncthreads();
            #pragma unroll
            for (int nf = 0; nf < 4; ++nf) {
                int base16 = (nf < 2) ? wn * 32 + nf * 16 : 128 + wn * 32 + (nf - 2) * 16;
                if (base16 >= p * 64 && base16 < p * 64 + 64) {
                    int cc = base16 - p * 64 + l15;
                    float bv_ = bias[colbase + base16 + l15];
                    #pragma unroll
                    for (int mf = 0; mf < 8; ++mf) {
                        int rowl = ((mf < 4) ? wm * 64 + mf * 16 : 128 + wm * 64 + (mf - 4) * 16) + l4 * 4;
                        bf16x4 v4;
                        #pragma unroll
                        for (int r = 0; r < 4; ++r)
                            v4[r] = (short)f2bf(acc[mf][nf][r] + bv_);
                        *(bf16x4*)&ldsT[cc * 264 + rowl] = v4;
                    }
                }
            }
            __syncthreads();
            #pragma unroll
            for (int it = 0; it < 4; ++it) {
                int uu = tid + it * 512;
                int cc = uu >> 5;
                int r0 = (uu & 31) * 8;
                bf16x8 val = *(const bf16x8*)&ldsT[cc * 264 + r0];
                int dg = colbase + p * 64 + cc;
                *(bf16x8*)(vt + ((size_t)(bidx * DD + dg)) * LL + lbase + r0) = val;
            }
        }
    }
}

// ---------------------------------------------------------------------------
// Kernel 3: S = q . k^T, lower-triangle 128x128 tiles (unchanged).
// ---------------------------------------------------------------------------
__global__ __launch_bounds__(256, 2) void sgemm_qk(
    const unsigned short* __restrict__ qkv,
    unsigned short* __restrict__ S)
{
    __shared__ __align__(16) unsigned short At[2][8192];
    __shared__ __align__(16) unsigned short Bt[2][8192];

    int wg = blockIdx.x;
    wg = (wg & 7) * 144 + (wg >> 3);
    const int b = wg / 36;
    const int t36 = wg % 36;
    int mt = 0, accq = 0;
    while (accq + mt + 1 <= t36) { ++mt; accq += mt; }
    const int nt = t36 - accq;

    const int tid  = threadIdx.x;
    const int lane = tid & 63;
    const int w    = tid >> 6;
    const int wr   = (w >> 1) * 64;
    const int wc   = (w & 1) * 64;
    const int l15  = lane & 15, l4 = lane >> 4;

    const int r8   = lane >> 3;
    const int swch = (lane & 7) ^ r8;

    const unsigned short* q = qkv;
    const unsigned short* k = qkv + MAT;
    const char* apanel = (const char*)(q + ((size_t)(b * LL) + mt * 128) * DD);
    const char* bpanel = (const char*)(k + ((size_t)(b * LL) + nt * 128) * DD);

    f32x4 acc[4][4];
    #pragma unroll
    for (int i = 0; i < 4; ++i)
        #pragma unroll
        for (int j = 0; j < 4; ++j)
            acc[i][j] = (f32x4){0.f, 0.f, 0.f, 0.f};

    #define STAGE_QK(KK, BUF) do {                                               \
        _Pragma("unroll")                                                        \
        for (int i2 = 0; i2 < 4; ++i2) {                                         \
            int grp = i2 * 4 + w;                                                \
            size_t rowoff = (size_t)(grp * 8 + r8) * 1024 + (KK) * 2 + swch * 16;\
            GLOAD_LDS16(apanel + rowoff, (char*)&At[BUF][0] + grp * 1024);       \
            GLOAD_LDS16(bpanel + rowoff, (char*)&Bt[BUF][0] + grp * 1024);       \
        }                                                                        \
    } while (0)

    STAGE_QK(0, 0);
    __syncthreads();

    for (int t = 0; t < 8; ++t) {
        const int cur = t & 1;
        if (t < 7) STAGE_QK((t + 1) * 64, cur ^ 1);

        const char* Ab = (const char*)&At[cur][0];
        const char* Bb = (const char*)&Bt[cur][0];
        #pragma unroll
        for (int ks = 0; ks < 2; ++ks) {
            bf16x8 af[4], bf_[4];
            const int ch = (ks * 4 + l4) ^ (l15 & 7);
            #pragma unroll
            for (int m = 0; m < 4; ++m)
                af[m] = *(const bf16x8*)(Ab + (wr + m * 16 + l15) * 128 + (ch << 4));
            #pragma unroll
            for (int n = 0; n < 4; ++n)
                bf_[n] = *(const bf16x8*)(Bb + (wc + n * 16 + l15) * 128 + (ch << 4));
            #pragma unroll
            for (int n = 0; n < 4; ++n)
                #pragma unroll
                for (int m = 0; m < 4; ++m)
                    acc[m][n] = __builtin_amdgcn_mfma_f32_16x16x32_bf16(af[m], bf_[n], acc[m][n], 0, 0, 0);
        }

        if (t < 7) publish_barrier();
    }
    #undef STAGE_QK

    unsigned short* sp = S + ((size_t)(b * LL) + mt * 128) * LL + nt * 128;
    #pragma unroll
    for (int n = 0; n < 4; ++n) {
        int col = wc + n * 16 + l15;
        #pragma unroll
        for (int m = 0; m < 4; ++m) {
            int row0 = wr + m * 16 + l4 * 4;
            #pragma unroll
            for (int r = 0; r < 4; ++r)
                sp[(size_t)(row0 + r) * LL + col] = f2bf(acc[m][n][r]);
        }
    }
}

// ---------------------------------------------------------------------------
// Kernel 4: row softmax v2 (unchanged).
// ---------------------------------------------------------------------------
__global__ __launch_bounds__(256) void softmax_rows(
    const unsigned short* __restrict__ S,
    const int* __restrict__ mask,
    unsigned short* __restrict__ P)
{
    __shared__ float mbias[1024];
    const int rc = blockIdx.x, b = blockIdx.y;
    const int tid = threadIdx.x, lane = tid & 63, w = tid >> 6;

    {
        const int* mp = mask + b * LL;
        #pragma unroll
        for (int j = 0; j < 4; ++j)
            mbias[tid * 4 + j] = mp[tid * 4 + j] ? 0.0f : -1e30f;
    }
    __syncthreads();

    const int j0 = lane * 16;
    const int limit = ((rc >> 2) + 1) << 7;
    for (int i = 0; i < 8; ++i) {
        const int r = rc * 32 + i * 4 + w;
        const unsigned short* srow = S + ((size_t)(b * LL) + r) * LL;

        bf16x8 v0 = {0,0,0,0,0,0,0,0}, v1 = {0,0,0,0,0,0,0,0};
        if (j0 <= r)     v0 = *(const bf16x8*)(srow + j0);
        if (j0 + 8 <= r) v1 = *(const bf16x8*)(srow + j0 + 8);

        float s[16];
        #pragma unroll
        for (int e = 0; e < 8; ++e) {
            int j = j0 + e;
            s[e]     = (j <= r)     ? bf2f((unsigned short)v0[e]) + mbias[j]     : -3e38f;
            s[8 + e] = (j + 8 <= r) ? bf2f((unsigned short)v1[e]) + mbias[j + 8] : -3e38f;
        }
        float mx = s[0];
        #pragma unroll
        for (int e = 1; e < 16; ++e) mx = fmaxf(mx, s[e]);
        mx = fmaxf(mx, __shfl_xor(mx, 1));
        mx = fmaxf(mx, __shfl_xor(mx, 2));
        mx = fmaxf(mx, __shfl_xor(mx, 4));
        mx = fmaxf(mx, __shfl_xor(mx, 8));
        mx = fmaxf(mx, __shfl_xor(mx, 16));
        mx = fmaxf(mx, __shfl_xor(mx, 32));

        float p[16], ls = 0.f;
        #pragma unroll
        for (int e = 0; e < 16; ++e) { p[e] = __expf(s[e] - mx); ls += p[e]; }
        ls += __shfl_xor(ls, 1);
        ls += __shfl_xor(ls, 2);
        ls += __shfl_xor(ls, 4);
        ls += __shfl_xor(ls, 8);
        ls += __shfl_xor(ls, 16);
        ls += __shfl_xor(ls, 32);
        const float inv = 1.0f / ls;

        if (j0 < limit) {
            bf16x8 o0, o1;
            #pragma unroll
            for (int e = 0; e < 8; ++e) {
                o0[e] = (short)f2bf(p[e] * inv);
                o1[e] = (short)f2bf(p[8 + e] * inv);
            }
            unsigned short* prow = P + ((size_t)(b * LL) + r) * LL;
            *(bf16x8*)(prow + j0)     = o0;
            *(bf16x8*)(prow + j0 + 8) = o1;
        }
    }
}

// ---------------------------------------------------------------------------
// Kernel 5: O = relu(P . V) via vt (unchanged from round 16).
// ---------------------------------------------------------------------------
__global__ __launch_bounds__(256, 2) void pv_gemm(
    const unsigned short* __restrict__ P,
    const unsigned short* __restrict__ vt,
    float* __restrict__ outp)
{
    __shared__ __align__(16) unsigned short At[2][8192];
    __shared__ __align__(16) unsigned short Bt[2][8192];

    int wg = blockIdx.x;
    wg = (wg & 7) * 128 + (wg >> 3);
    const int b  = wg >> 5;
    const int rr = wg & 31;
    const int idx = rr >> 2;
    const int rt = (idx & 1) ? ((idx - 1) >> 1) : (7 - (idx >> 1));  // 7,0,6,1,5,2,4,3
    const int ct = rr & 3;

    const int tid  = threadIdx.x;
    const int lane = tid & 63;
    const int w    = tid >> 6;
    const int wr   = (w >> 1) * 64;
    const int wc   = (w & 1) * 64;
    const int l15  = lane & 15, l4 = lane >> 4;

    const int r8   = lane >> 3;
    const int swch = (lane & 7) ^ r8;

    const char* apanel = (const char*)(P  + ((size_t)(b * LL) + rt * 128) * LL);
    const char* bpanel = (const char*)(vt + ((size_t)(b * DD) + ct * 128) * LL);

    const int NT = (rt + 1) * 2;

    f32x4 acc[4][4];
    #pragma unroll
    for (int i = 0; i < 4; ++i)
        #pragma unroll
        for (int j = 0; j < 4; ++j)
            acc[i][j] = (f32x4){0.f, 0.f, 0.f, 0.f};

    #define STAGE_PV(KK, BUF) do {                                               \
        _Pragma("unroll")                                                        \
        for (int i2 = 0; i2 < 4; ++i2) {                                         \
            int grp = i2 * 4 + w;                                                \
            size_t rowoff = (size_t)(grp * 8 + r8) * 2048 + (KK) * 2 + swch * 16;\
            GLOAD_LDS16(apanel + rowoff, (char*)&At[BUF][0] + grp * 1024);       \
            GLOAD_LDS16(bpanel + rowoff, (char*)&Bt[BUF][0] + grp * 1024);       \
        }                                                                        \
    } while (0)

    STAGE_PV(0, 0);
    __syncthreads();

    for (int t = 0; t < NT; ++t) {
        const int cur = t & 1;
        if (t < NT - 1) STAGE_PV((t + 1) * 64, cur ^ 1);

        const char* Ab = (const char*)&At[cur][0];
        const char* Bb = (const char*)&Bt[cur][0];
        #pragma unroll
        for (int ks = 0; ks < 2; ++ks) {
            bf16x8 af[4], bf_[4];
            const int ch = (ks * 4 + l4) ^ (l15 & 7);
            #pragma unroll
            for (int m = 0; m < 4; ++m)
                af[m] = *(const bf16x8*)(Ab + (wr + m * 16 + l15) * 128 + (ch << 4));
            #pragma unroll
            for (int n = 0; n < 4; ++n)
                bf_[n] = *(const bf16x8*)(Bb + (wc + n * 16 + l15) * 128 + (ch << 4));
            #pragma unroll
            for (int n = 0; n < 4; ++n)
                #pragma unroll
                for (int m = 0; m < 4; ++m)
                    acc[m][n] = __builtin_amdgcn_mfma_f32_16x16x32_bf16(af[m], bf_[n], acc[m][n], 0, 0, 0);
        }

        if (t < NT - 1) publish_barrier();
    }
    #undef STAGE_PV

    float* op = outp + ((size_t)(b * LL) + rt * 128) * DD + ct * 128;
    #pragma unroll
    for (int n = 0; n < 4; ++n) {
        int col = wc + n * 16 + l15;
        #pragma unroll
        for (int m = 0; m < 4; ++m) {
            int row0 = wr + m * 16 + l4 * 4;
            #pragma unroll
            for (int r = 0; r < 4; ++r)
                op[(size_t)(row0 + r) * DD + col] = fmaxf(acc[m][n][r], 0.f);
        }
    }
}

extern "C" void kernel_launch(void* const* d_in, const int* in_sizes, int n_in,
                              void* d_out, int out_size, void* d_ws, size_t ws_size,
                              hipStream_t stream) {
    const float* x  = (const float*)d_in[0];
    const float* Wq = (const float*)d_in[1];
    const float* bq = (const float*)d_in[2];
    const float* Wk = (const float*)d_in[3];
    const float* bk = (const float*)d_in[4];
    const float* Wv = (const float*)d_in[5];
    const float* bv = (const float*)d_in[6];
    const int* mask = (const int*)d_in[7];

    unsigned short* qkv = (unsigned short*)d_ws;          // q | k (2 x 32MB)
    unsigned short* vtp = qkv + 2 * MAT;                  // vt [b][d][l] (32MB)
    unsigned short* Wb  = qkv + 3 * MAT;                  // W bf16 (3MB)
    unsigned short* xb  = (unsigned short*)d_out;         // x bf16 (64MB), dead after proj
    unsigned short* S   = (unsigned short*)d_out;         // S bf16 (64MB), overwrites xb
    unsigned short* Pp  = qkv;                            // P bf16 over q+k (dead)
    float* out = (float*)d_out;                           // final O overwrites S

    cast_all<<<2048, 256, 0, stream>>>(x, Wq, Wk, Wv, xb, Wb);
    qkv_proj6b<<<dim3(256, 3), 512, 0, stream>>>(xb, Wb, bq, bk, bv, qkv, vtp);
    sgemm_qk<<<dim3(1152), 256, 0, stream>>>(qkv, S);
    softmax_rows<<<dim3(32, 32), 256, 0, stream>>>(S, mask, Pp);
    pv_gemm<<<dim3(1024), 256, 0, stream>>>(Pp, vtp, out);
}

// Round 18
// 237.175 us; speedup vs baseline: 1.1927x; 1.0091x over previous
//
#include <hip/hip_runtime.h>
#include <hip/hip_bf16.h>
#include <stdint.h>

#define DM 1024   // d_model
#define DD 512    // d (proj out / head dim)
#define BB 32     // batch
#define LL 1024   // seq len
#define SCALE 0.04419417382415922f  // 1/sqrt(512)
#define MAT ((size_t)BB * LL * DD)  // elems per q/k/v matrix

typedef float f32x4 __attribute__((ext_vector_type(4)));
typedef short bf16x8 __attribute__((ext_vector_type(8)));
typedef short bf16x4 __attribute__((ext_vector_type(4)));

__device__ inline unsigned short f2bf(float f) {
    union { float f; uint32_t u; } v; v.f = f;
    uint32_t r = v.u + 0x7fffu + ((v.u >> 16) & 1u);
    return (unsigned short)(r >> 16);
}
__device__ inline float bf2f(unsigned short u) {
    union { uint32_t u; float f; } v; v.u = ((uint32_t)u) << 16;
    return v.f;
}

__device__ inline bf16x4 cvt4(f32x4 a, float s) {
    bf16x4 r;
    r[0] = (short)f2bf(a[0] * s);
    r[1] = (short)f2bf(a[1] * s);
    r[2] = (short)f2bf(a[2] * s);
    r[3] = (short)f2bf(a[3] * s);
    return r;
}

#define GLOAD_LDS16(gsrc, ldst) \
    __builtin_amdgcn_global_load_lds((const __attribute__((address_space(1))) unsigned int*)(gsrc), \
        (__attribute__((address_space(3))) unsigned int*)(ldst), 16, 0, 0)

__device__ inline void publish_barrier() {
    asm volatile("s_waitcnt vmcnt(0)" ::: "memory");
    __builtin_amdgcn_sched_barrier(0);
    __builtin_amdgcn_s_barrier();
    __builtin_amdgcn_sched_barrier(0);
}
__device__ inline void gate8() {
    asm volatile("s_waitcnt vmcnt(8)" ::: "memory");
    __builtin_amdgcn_sched_barrier(0);
    __builtin_amdgcn_s_barrier();
    __builtin_amdgcn_sched_barrier(0);
}
__device__ inline void gate6() {
    asm volatile("s_waitcnt vmcnt(6)" ::: "memory");
    __builtin_amdgcn_sched_barrier(0);
    __builtin_amdgcn_s_barrier();
    __builtin_amdgcn_sched_barrier(0);
}
__device__ inline void gate2() {
    asm volatile("s_waitcnt vmcnt(2)" ::: "memory");
    __builtin_amdgcn_sched_barrier(0);
    __builtin_amdgcn_s_barrier();
    __builtin_amdgcn_sched_barrier(0);
}
__device__ inline void gate0() {
    asm volatile("s_waitcnt vmcnt(0)" ::: "memory");
    __builtin_amdgcn_sched_barrier(0);
    __builtin_amdgcn_s_barrier();
    __builtin_amdgcn_sched_barrier(0);
}

// ---------------------------------------------------------------------------
// Kernel 0: fused casts, grid-stride over 2048 blocks.
// ---------------------------------------------------------------------------
#define NCHUNK (16384 * 256 + 768 * 256)
__global__ __launch_bounds__(256) void cast_all(const float* __restrict__ x,
                                                const float* __restrict__ Wq,
                                                const float* __restrict__ Wk,
                                                const float* __restrict__ Wv,
                                                unsigned short* __restrict__ xb,
                                                unsigned short* __restrict__ Wb)
{
    for (size_t idx = (size_t)blockIdx.x * 256 + threadIdx.x; idx < NCHUNK;
         idx += (size_t)2048 * 256) {
        if (idx < (size_t)16384 * 256) {
            size_t base = idx * 8;
            f32x4 a = *(const f32x4*)(x + base);
            f32x4 b = *(const f32x4*)(x + base + 4);
            bf16x4 lo = cvt4(a, 1.0f), hi = cvt4(b, 1.0f);
            bf16x8 o = {lo[0], lo[1], lo[2], lo[3], hi[0], hi[1], hi[2], hi[3]};
            *(bf16x8*)(xb + base) = o;
        } else {
            size_t wi = idx - (size_t)16384 * 256;
            int o = (int)(wi >> 16);
            size_t rem = wi & 65535;
            const float* W = (o == 0) ? Wq : (o == 1) ? Wk : Wv;
            float s = (o == 0) ? SCALE : 1.0f;
            size_t base = rem * 8;
            f32x4 a = *(const f32x4*)(W + base);
            f32x4 b = *(const f32x4*)(W + base + 4);
            bf16x4 lo = cvt4(a, s), hi = cvt4(b, s);
            bf16x8 out = {lo[0], lo[1], lo[2], lo[3], hi[0], hi[1], hi[2], hi[3]};
            *(bf16x8*)(Wb + (size_t)o * 524288 + base) = out;
        }
    }
}

// ---------------------------------------------------------------------------
// Kernel 1: q/k/v projection v6c — TWO barriers per K-tile (r17's 3-barrier
// merge gave −10%; same lever again). Per tile:
//  P01: stage A0(t+1),B0(t+1); gate6 [steady 8 in flight, pops B1(t) —
//       L2-served W load with a full burst+barrier of flight];
//       read A0,B0,B1 frags; Q0+Q1 = 32 MFMA.
//  P23: stage B1(t+1),A1(t+1); gate8 [10 in flight, pops A1(t) — x load
//       with a full tile of flight]; read A1 frags; Q2+Q3 = 32 MFMA.
// Prologue: 12 in flight at first gate6 -> pops A0(0),B0(0),B1(0); queue
// composition identical to steady state. Tail: gate2 / gate0.
// WAR: every buffer overwrite >=2 gates after its last read.
// V output (o==2): LDS-transpose epilogue -> vt[b][d][l].
// ---------------------------------------------------------------------------
__global__ __launch_bounds__(512, 2) void qkv_proj6c(
    const unsigned short* __restrict__ xb,
    const unsigned short* __restrict__ Wb,
    const float* __restrict__ bq, const float* __restrict__ bk, const float* __restrict__ bv,
    unsigned short* __restrict__ qkv,     // q at 0, k at MAT
    unsigned short* __restrict__ vt)      // [b][d][l]
{
    __shared__ __align__(16) unsigned short AL[2][2][8192];
    __shared__ __align__(16) unsigned short BL[2][2][8192];

    const int o = blockIdx.y;
    const float* bias = (o == 0) ? bq : (o == 1) ? bk : bv;
    const float wscale = (o == 0) ? SCALE : 1.0f;
    const unsigned short* W = Wb + (size_t)o * 524288;
    unsigned short* out = qkv + (size_t)o * MAT;

    int wg = blockIdx.x;
    wg = (wg & 7) * 32 + (wg >> 3);
    const int mt = wg >> 1, nt = wg & 1;
    const int rowbase = mt * 256;
    const int colbase = nt * 256;

    const int tid  = threadIdx.x;
    const int lane = tid & 63;
    const int w    = tid >> 6;
    const int wm   = w >> 2;
    const int wn   = w & 3;
    const int l15  = lane & 15, l4 = lane >> 4;
    const int rxor = l15 & 7;

    const int r8   = lane >> 3;
    const int swch = (lane & 7) ^ r8;

    const char* xpanel = (const char*)(xb + (size_t)rowbase * DM);
    const char* wpanel = (const char*)(W  + (size_t)colbase * DM);

    #define STAGE_HALF(panel, T, H, slot) do {                                   \
        _Pragma("unroll")                                                        \
        for (int i2 = 0; i2 < 2; ++i2) {                                         \
            int grp = i2 * 8 + w;                                                \
            GLOAD_LDS16((panel) + ((size_t)((H) * 128 + grp * 8 + r8) * 2048)    \
                            + (size_t)(T) * 128 + swch * 16,                     \
                        (char*)(slot) + grp * 1024);                             \
        }                                                                        \
    } while (0)

    #define RDA(base, mf4, ks) (*(const bf16x8*)((base) + (wm * 64 + (mf4) * 16 + l15) * 128 \
                            + ((((ks) * 4 + l4) ^ rxor) << 4)))
    #define RDB(base, nfl, ks) (*(const bf16x8*)((base) + (wn * 32 + (nfl) * 16 + l15) * 128 \
                            + ((((ks) * 4 + l4) ^ rxor) << 4)))

    f32x4 acc[8][4];
    #pragma unroll
    for (int i = 0; i < 8; ++i)
        #pragma unroll
        for (int j = 0; j < 4; ++j)
            acc[i][j] = (f32x4){0.f, 0.f, 0.f, 0.f};

    bf16x8 aF[4][2], bF[4][2];

    STAGE_HALF(xpanel, 0, 0, &AL[0][0][0]);   // A0(0)
    STAGE_HALF(wpanel, 0, 0, &BL[0][0][0]);   // B0(0)
    STAGE_HALF(wpanel, 0, 1, &BL[0][1][0]);   // B1(0)
    STAGE_HALF(xpanel, 0, 1, &AL[0][1][0]);   // A1(0)

    for (int t = 0; t < 16; ++t) {
        const int c = t & 1, cn = c ^ 1;
        const char* A0b = (const char*)&AL[c][0][0];
        const char* A1b = (const char*)&AL[c][1][0];
        const char* B0b = (const char*)&BL[c][0][0];
        const char* B1b = (const char*)&BL[c][1][0];
        const bool st = (t < 15);

        // ---- phase 0+1: (A0,B0) + (A0,B1) ----
        if (st) {
            STAGE_HALF(xpanel, t + 1, 0, &AL[cn][0][0]);
            STAGE_HALF(wpanel, t + 1, 0, &BL[cn][0][0]);
            gate6();
        } else gate2();
        #pragma unroll
        for (int ks = 0; ks < 2; ++ks) {
            #pragma unroll
            for (int mf = 0; mf < 4; ++mf) aF[mf][ks] = RDA(A0b, mf, ks);
            bF[0][ks] = RDB(B0b, 0, ks);
            bF[1][ks] = RDB(B0b, 1, ks);
            bF[2][ks] = RDB(B1b, 0, ks);
            bF[3][ks] = RDB(B1b, 1, ks);
        }
        #pragma unroll
        for (int ks = 0; ks < 2; ++ks)
            #pragma unroll
            for (int nf = 0; nf < 4; ++nf)
                #pragma unroll
                for (int mf = 0; mf < 4; ++mf)
                    acc[mf][nf] = __builtin_amdgcn_mfma_f32_16x16x32_bf16(aF[mf][ks], bF[nf][ks], acc[mf][nf], 0, 0, 0);

        // ---- phase 2+3: (A1,B0) + (A1,B1) ----
        if (st) {
            STAGE_HALF(wpanel, t + 1, 1, &BL[cn][1][0]);
            STAGE_HALF(xpanel, t + 1, 1, &AL[cn][1][0]);
            gate8();
        } else gate0();
        #pragma unroll
        for (int ks = 0; ks < 2; ++ks)
            #pragma unroll
            for (int mf = 0; mf < 4; ++mf) aF[mf][ks] = RDA(A1b, mf, ks);
        #pragma unroll
        for (int ks = 0; ks < 2; ++ks)
            #pragma unroll
            for (int nf = 0; nf < 4; ++nf)
                #pragma unroll
                for (int mf = 0; mf < 4; ++mf)
                    acc[4 + mf][nf] = __builtin_amdgcn_mfma_f32_16x16x32_bf16(aF[mf][ks], bF[nf][ks], acc[4 + mf][nf], 0, 0, 0);
    }
    #undef STAGE_HALF
    #undef RDA
    #undef RDB

    if (o != 2) {
        #pragma unroll
        for (int nf = 0; nf < 4; ++nf) {
            int col = colbase + ((nf < 2) ? wn * 32 + nf * 16 : 128 + wn * 32 + (nf - 2) * 16) + l15;
            float bv_ = bias[col] * wscale;
            #pragma unroll
            for (int mf = 0; mf < 8; ++mf) {
                int row0 = rowbase + ((mf < 4) ? wm * 64 + mf * 16 : 128 + wm * 64 + (mf - 4) * 16) + l4 * 4;
                #pragma unroll
                for (int r = 0; r < 4; ++r)
                    out[(size_t)(row0 + r) * DD + col] = f2bf(acc[mf][nf][r] + bv_);
            }
        }
    } else {
        // ---- V epilogue: transpose 256x256 tile via LDS -> vt[b][d][l] ----
        unsigned short* ldsT = (unsigned short*)&AL[0][0][0];
        const int bidx  = rowbase >> 10;
        const int lbase = rowbase & 1023;
        #pragma unroll
        for (int p = 0; p < 4; ++p) {
            __syncthreads();
            #pragma unroll
            for (int nf = 0; nf < 4; ++nf) {
                int base16 = (nf < 2) ? wn * 32 + nf * 16 : 128 + wn * 32 + (nf - 2) * 16;
                if (base16 >= p * 64 && base16 < p * 64 + 64) {
                    int cc = base16 - p * 64 + l15;
                    float bv_ = bias[colbase + base16 + l15];
                    #pragma unroll
                    for (int mf = 0; mf < 8; ++mf) {
                        int rowl = ((mf < 4) ? wm * 64 + mf * 16 : 128 + wm * 64 + (mf - 4) * 16) + l4 * 4;
                        bf16x4 v4;
                        #pragma unroll
                        for (int r = 0; r < 4; ++r)
                            v4[r] = (short)f2bf(acc[mf][nf][r] + bv_);
                        *(bf16x4*)&ldsT[cc * 264 + rowl] = v4;
                    }
                }
            }
            __syncthreads();
            #pragma unroll
            for (int it = 0; it < 4; ++it) {
                int uu = tid + it * 512;
                int cc = uu >> 5;
                int r0 = (uu & 31) * 8;
                bf16x8 val = *(const bf16x8*)&ldsT[cc * 264 + r0];
                int dg = colbase + p * 64 + cc;
                *(bf16x8*)(vt + ((size_t)(bidx * DD + dg)) * LL + lbase + r0) = val;
            }
        }
    }
}

// ---------------------------------------------------------------------------
// Kernel 3: S = q . k^T, lower-triangle 128x128 tiles (unchanged).
// ---------------------------------------------------------------------------
__global__ __launch_bounds__(256, 2) void sgemm_qk(
    const unsigned short* __restrict__ qkv,
    unsigned short* __restrict__ S)
{
    __shared__ __align__(16) unsigned short At[2][8192];
    __shared__ __align__(16) unsigned short Bt[2][8192];

    int wg = blockIdx.x;
    wg = (wg & 7) * 144 + (wg >> 3);
    const int b = wg / 36;
    const int t36 = wg % 36;
    int mt = 0, accq = 0;
    while (accq + mt + 1 <= t36) { ++mt; accq += mt; }
    const int nt = t36 - accq;

    const int tid  = threadIdx.x;
    const int lane = tid & 63;
    const int w    = tid >> 6;
    const int wr   = (w >> 1) * 64;
    const int wc   = (w & 1) * 64;
    const int l15  = lane & 15, l4 = lane >> 4;

    const int r8   = lane >> 3;
    const int swch = (lane & 7) ^ r8;

    const unsigned short* q = qkv;
    const unsigned short* k = qkv + MAT;
    const char* apanel = (const char*)(q + ((size_t)(b * LL) + mt * 128) * DD);
    const char* bpanel = (const char*)(k + ((size_t)(b * LL) + nt * 128) * DD);

    f32x4 acc[4][4];
    #pragma unroll
    for (int i = 0; i < 4; ++i)
        #pragma unroll
        for (int j = 0; j < 4; ++j)
            acc[i][j] = (f32x4){0.f, 0.f, 0.f, 0.f};

    #define STAGE_QK(KK, BUF) do {                                               \
        _Pragma("unroll")                                                        \
        for (int i2 = 0; i2 < 4; ++i2) {                                         \
            int grp = i2 * 4 + w;                                                \
            size_t rowoff = (size_t)(grp * 8 + r8) * 1024 + (KK) * 2 + swch * 16;\
            GLOAD_LDS16(apanel + rowoff, (char*)&At[BUF][0] + grp * 1024);       \
            GLOAD_LDS16(bpanel + rowoff, (char*)&Bt[BUF][0] + grp * 1024);       \
        }                                                                        \
    } while (0)

    STAGE_QK(0, 0);
    __syncthreads();

    for (int t = 0; t < 8; ++t) {
        const int cur = t & 1;
        if (t < 7) STAGE_QK((t + 1) * 64, cur ^ 1);

        const char* Ab = (const char*)&At[cur][0];
        const char* Bb = (const char*)&Bt[cur][0];
        #pragma unroll
        for (int ks = 0; ks < 2; ++ks) {
            bf16x8 af[4], bf_[4];
            const int ch = (ks * 4 + l4) ^ (l15 & 7);
            #pragma unroll
            for (int m = 0; m < 4; ++m)
                af[m] = *(const bf16x8*)(Ab + (wr + m * 16 + l15) * 128 + (ch << 4));
            #pragma unroll
            for (int n = 0; n < 4; ++n)
                bf_[n] = *(const bf16x8*)(Bb + (wc + n * 16 + l15) * 128 + (ch << 4));
            #pragma unroll
            for (int n = 0; n < 4; ++n)
                #pragma unroll
                for (int m = 0; m < 4; ++m)
                    acc[m][n] = __builtin_amdgcn_mfma_f32_16x16x32_bf16(af[m], bf_[n], acc[m][n], 0, 0, 0);
        }

        if (t < 7) publish_barrier();
    }
    #undef STAGE_QK

    unsigned short* sp = S + ((size_t)(b * LL) + mt * 128) * LL + nt * 128;
    #pragma unroll
    for (int n = 0; n < 4; ++n) {
        int col = wc + n * 16 + l15;
        #pragma unroll
        for (int m = 0; m < 4; ++m) {
            int row0 = wr + m * 16 + l4 * 4;
            #pragma unroll
            for (int r = 0; r < 4; ++r)
                sp[(size_t)(row0 + r) * LL + col] = f2bf(acc[m][n][r]);
        }
    }
}

// ---------------------------------------------------------------------------
// Kernel 4: row softmax v2 (unchanged).
// ---------------------------------------------------------------------------
__global__ __launch_bounds__(256) void softmax_rows(
    const unsigned short* __restrict__ S,
    const int* __restrict__ mask,
    unsigned short* __restrict__ P)
{
    __shared__ float mbias[1024];
    const int rc = blockIdx.x, b = blockIdx.y;
    const int tid = threadIdx.x, lane = tid & 63, w = tid >> 6;

    {
        const int* mp = mask + b * LL;
        #pragma unroll
        for (int j = 0; j < 4; ++j)
            mbias[tid * 4 + j] = mp[tid * 4 + j] ? 0.0f : -1e30f;
    }
    __syncthreads();

    const int j0 = lane * 16;
    const int limit = ((rc >> 2) + 1) << 7;
    for (int i = 0; i < 8; ++i) {
        const int r = rc * 32 + i * 4 + w;
        const unsigned short* srow = S + ((size_t)(b * LL) + r) * LL;

        bf16x8 v0 = {0,0,0,0,0,0,0,0}, v1 = {0,0,0,0,0,0,0,0};
        if (j0 <= r)     v0 = *(const bf16x8*)(srow + j0);
        if (j0 + 8 <= r) v1 = *(const bf16x8*)(srow + j0 + 8);

        float s[16];
        #pragma unroll
        for (int e = 0; e < 8; ++e) {
            int j = j0 + e;
            s[e]     = (j <= r)     ? bf2f((unsigned short)v0[e]) + mbias[j]     : -3e38f;
            s[8 + e] = (j + 8 <= r) ? bf2f((unsigned short)v1[e]) + mbias[j + 8] : -3e38f;
        }
        float mx = s[0];
        #pragma unroll
        for (int e = 1; e < 16; ++e) mx = fmaxf(mx, s[e]);
        mx = fmaxf(mx, __shfl_xor(mx, 1));
        mx = fmaxf(mx, __shfl_xor(mx, 2));
        mx = fmaxf(mx, __shfl_xor(mx, 4));
        mx = fmaxf(mx, __shfl_xor(mx, 8));
        mx = fmaxf(mx, __shfl_xor(mx, 16));
        mx = fmaxf(mx, __shfl_xor(mx, 32));

        float p[16], ls = 0.f;
        #pragma unroll
        for (int e = 0; e < 16; ++e) { p[e] = __expf(s[e] - mx); ls += p[e]; }
        ls += __shfl_xor(ls, 1);
        ls += __shfl_xor(ls, 2);
        ls += __shfl_xor(ls, 4);
        ls += __shfl_xor(ls, 8);
        ls += __shfl_xor(ls, 16);
        ls += __shfl_xor(ls, 32);
        const float inv = 1.0f / ls;

        if (j0 < limit) {
            bf16x8 o0, o1;
            #pragma unroll
            for (int e = 0; e < 8; ++e) {
                o0[e] = (short)f2bf(p[e] * inv);
                o1[e] = (short)f2bf(p[8 + e] * inv);
            }
            unsigned short* prow = P + ((size_t)(b * LL) + r) * LL;
            *(bf16x8*)(prow + j0)     = o0;
            *(bf16x8*)(prow + j0 + 8) = o1;
        }
    }
}

// ---------------------------------------------------------------------------
// Kernel 5: O = relu(P . V) via vt (unchanged).
// ---------------------------------------------------------------------------
__global__ __launch_bounds__(256, 2) void pv_gemm(
    const unsigned short* __restrict__ P,
    const unsigned short* __restrict__ vt,
    float* __restrict__ outp)
{
    __shared__ __align__(16) unsigned short At[2][8192];
    __shared__ __align__(16) unsigned short Bt[2][8192];

    int wg = blockIdx.x;
    wg = (wg & 7) * 128 + (wg >> 3);
    const int b  = wg >> 5;
    const int rr = wg & 31;
    const int idx = rr >> 2;
    const int rt = (idx & 1) ? ((idx - 1) >> 1) : (7 - (idx >> 1));  // 7,0,6,1,5,2,4,3
    const int ct = rr & 3;

    const int tid  = threadIdx.x;
    const int lane = tid & 63;
    const int w    = tid >> 6;
    const int wr   = (w >> 1) * 64;
    const int wc   = (w & 1) * 64;
    const int l15  = lane & 15, l4 = lane >> 4;

    const int r8   = lane >> 3;
    const int swch = (lane & 7) ^ r8;

    const char* apanel = (const char*)(P  + ((size_t)(b * LL) + rt * 128) * LL);
    const char* bpanel = (const char*)(vt + ((size_t)(b * DD) + ct * 128) * LL);

    const int NT = (rt + 1) * 2;

    f32x4 acc[4][4];
    #pragma unroll
    for (int i = 0; i < 4; ++i)
        #pragma unroll
        for (int j = 0; j < 4; ++j)
            acc[i][j] = (f32x4){0.f, 0.f, 0.f, 0.f};

    #define STAGE_PV(KK, BUF) do {                                               \
        _Pragma("unroll")                                                        \
        for (int i2 = 0; i2 < 4; ++i2) {                                         \
            int grp = i2 * 4 + w;                                                \
            size_t rowoff = (size_t)(grp * 8 + r8) * 2048 + (KK) * 2 + swch * 16;\
            GLOAD_LDS16(apanel + rowoff, (char*)&At[BUF][0] + grp * 1024);       \
            GLOAD_LDS16(bpanel + rowoff, (char*)&Bt[BUF][0] + grp * 1024);       \
        }                                                                        \
    } while (0)

    STAGE_PV(0, 0);
    __syncthreads();

    for (int t = 0; t < NT; ++t) {
        const int cur = t & 1;
        if (t < NT - 1) STAGE_PV((t + 1) * 64, cur ^ 1);

        const char* Ab = (const char*)&At[cur][0];
        const char* Bb = (const char*)&Bt[cur][0];
        #pragma unroll
        for (int ks = 0; ks < 2; ++ks) {
            bf16x8 af[4], bf_[4];
            const int ch = (ks * 4 + l4) ^ (l15 & 7);
            #pragma unroll
            for (int m = 0; m < 4; ++m)
                af[m] = *(const bf16x8*)(Ab + (wr + m * 16 + l15) * 128 + (ch << 4));
            #pragma unroll
            for (int n = 0; n < 4; ++n)
                bf_[n] = *(const bf16x8*)(Bb + (wc + n * 16 + l15) * 128 + (ch << 4));
            #pragma unroll
            for (int n = 0; n < 4; ++n)
                #pragma unroll
                for (int m = 0; m < 4; ++m)
                    acc[m][n] = __builtin_amdgcn_mfma_f32_16x16x32_bf16(af[m], bf_[n], acc[m][n], 0, 0, 0);
        }

        if (t < NT - 1) publish_barrier();
    }
    #undef STAGE_PV

    float* op = outp + ((size_t)(b * LL) + rt * 128) * DD + ct * 128;
    #pragma unroll
    for (int n = 0; n < 4; ++n) {
        int col = wc + n * 16 + l15;
        #pragma unroll
        for (int m = 0; m < 4; ++m) {
            int row0 = wr + m * 16 + l4 * 4;
            #pragma unroll
            for (int r = 0; r < 4; ++r)
                op[(size_t)(row0 + r) * DD + col] = fmaxf(acc[m][n][r], 0.f);
        }
    }
}

extern "C" void kernel_launch(void* const* d_in, const int* in_sizes, int n_in,
                              void* d_out, int out_size, void* d_ws, size_t ws_size,
                              hipStream_t stream) {
    const float* x  = (const float*)d_in[0];
    const float* Wq = (const float*)d_in[1];
    const float* bq = (const float*)d_in[2];
    const float* Wk = (const float*)d_in[3];
    const float* bk = (const float*)d_in[4];
    const float* Wv = (const float*)d_in[5];
    const float* bv = (const float*)d_in[6];
    const int* mask = (const int*)d_in[7];

    unsigned short* qkv = (unsigned short*)d_ws;          // q | k (2 x 32MB)
    unsigned short* vtp = qkv + 2 * MAT;                  // vt [b][d][l] (32MB)
    unsigned short* Wb  = qkv + 3 * MAT;                  // W bf16 (3MB)
    unsigned short* xb  = (unsigned short*)d_out;         // x bf16 (64MB), dead after proj
    unsigned short* S   = (unsigned short*)d_out;         // S bf16 (64MB), overwrites xb
    unsigned short* Pp  = qkv;                            // P bf16 over q+k (dead)
    float* out = (float*)d_out;                           // final O overwrites S

    cast_all<<<2048, 256, 0, stream>>>(x, Wq, Wk, Wv, xb, Wb);
    qkv_proj6c<<<dim3(256, 3), 512, 0, stream>>>(xb, Wb, bq, bk, bv, qkv, vtp);
    sgemm_qk<<<dim3(1152), 256, 0, stream>>>(qkv, S);
    softmax_rows<<<dim3(32, 32), 256, 0, stream>>>(S, mask, Pp);
    pv_gemm<<<dim3(1024), 256, 0, stream>>>(Pp, vtp, out);
}